// Round 16
// baseline (550.771 us; speedup 1.0000x reference)
//
#include <hip/hip_runtime.h>
#include <cfloat>

#define N_NODES 4096
#define C1_DIM  1001
#define D_DIM   4096
#define HMLP    1024
#define KCAT    (D_DIM + C1_DIM + 4)   // 5101
#define K1PAD   5120                   // padded, multiple of 32
#define TOPK    32

typedef unsigned short u16;
typedef __bf16 bf16x8 __attribute__((ext_vector_type(8)));
typedef float  f32x4  __attribute__((ext_vector_type(4)));

// RNE round-to-bf16 (round-4-proven numerics).
__device__ __forceinline__ unsigned rne_bits(float x) {
  const unsigned u = __float_as_uint(x);
  return u + 0x7FFFu + ((u >> 16) & 1u);
}

__device__ __forceinline__ void gload16(const void* g, void* l) {
  __builtin_amdgcn_global_load_lds(
      (const __attribute__((address_space(1))) unsigned int*)g,
      (__attribute__((address_space(3))) unsigned int*)l, 16, 0, 0);
}

// ---------------------------------------------------------------------------
// a_split: build a_hi/a_lo [4096][5120] planes in one pass.
// ---------------------------------------------------------------------------
__global__ __launch_bounds__(256) void a_split(
    const float* __restrict__ query, const float* __restrict__ probs,
    const float* __restrict__ bbox,
    u16* __restrict__ hi, u16* __restrict__ lo) {
  const size_t idx = ((size_t)blockIdx.x * 256 + threadIdx.x) * 8;
  const int row = (int)(idx / K1PAD);
  const int col = (int)(idx - (size_t)row * K1PAD);
  float xs[8];
  if (col < D_DIM) {
    const float4 x0 = *(const float4*)(query + (size_t)row * D_DIM + col);
    const float4 x1 = *(const float4*)(query + (size_t)row * D_DIM + col + 4);
    xs[0]=x0.x; xs[1]=x0.y; xs[2]=x0.z; xs[3]=x0.w;
    xs[4]=x1.x; xs[5]=x1.y; xs[6]=x1.z; xs[7]=x1.w;
  } else {
#pragma unroll
    for (int e = 0; e < 8; ++e) {
      const int c = col + e - D_DIM;
      xs[e] = (c < C1_DIM) ? probs[(size_t)row * C1_DIM + c]
            : (c < C1_DIM + 4) ? bbox[(size_t)row * 4 + (c - C1_DIM)] : 0.f;
    }
  }
  unsigned hw[4], lw[4];
#pragma unroll
  for (int p = 0; p < 4; ++p) {
    const unsigned v0 = rne_bits(xs[2*p]);
    const unsigned v1 = rne_bits(xs[2*p+1]);
    hw[p] = (v1 & 0xFFFF0000u) | (v0 >> 16);
    const float r0 = xs[2*p]   - __uint_as_float(v0 & 0xFFFF0000u);
    const float r1 = xs[2*p+1] - __uint_as_float(v1 & 0xFFFF0000u);
    lw[p] = (rne_bits(r1) & 0xFFFF0000u) | (rne_bits(r0) >> 16);
  }
  *(uint4*)(hi + idx) = make_uint4(hw[0], hw[1], hw[2], hw[3]);
  *(uint4*)(lo + idx) = make_uint4(lw[0], lw[1], lw[2], lw[3]);
}

// ---------------------------------------------------------------------------
// out_hi/lo[C][Rpad] = split-bf16 (RNE) transpose of in[R][C] (zero pad r>=R)
// ---------------------------------------------------------------------------
__global__ __launch_bounds__(256) void transpose_split(
    const float* __restrict__ in, int R, int C, int Rpad,
    u16* __restrict__ out_hi, u16* __restrict__ out_lo) {
  __shared__ float t[64][65];
  const int rb = blockIdx.x * 64;
  const int cb = blockIdx.y * 64;
  const int tid = threadIdx.x;
  const int lr = tid >> 6, lc = tid & 63;
#pragma unroll
  for (int i = 0; i < 16; ++i) {
    const int r = lr + i * 4;
    const int gr = rb + r;
    t[r][lc] = (gr < R) ? in[(size_t)gr * C + cb + lc] : 0.f;
  }
  __syncthreads();
#pragma unroll
  for (int i = 0; i < 16; ++i) {
    const int c = lr + i * 4;
    const float v = t[lc][c];
    const unsigned vh = rne_bits(v);
    const float r = v - __uint_as_float(vh & 0xFFFF0000u);
    const size_t o = (size_t)(cb + c) * Rpad + rb + lc;
    out_hi[o] = (u16)(vh >> 16);
    out_lo[o] = (u16)(rne_bits(r) >> 16);
  }
}

// ===========================================================================
// u16-plane swizzle (r9-proven, 0 conflicts): stored 16B-chunk =
// logical ^ ((row>>1)&3); gload SOURCE pre-swizzled (sk), LDS dest linear;
// reads use ko_swz. fp32-A swizzle (Z1): stored = logical ^ (row&7).
// ===========================================================================

template<bool RELU, bool OUT_SPLIT, bool HASBIAS>
__device__ __forceinline__ void epilogue_64(
    f32x4 (&acc)[4][2], int row0, int col0, int wr0, int wc0, int lane,
    const float* bias, float* Cf, u16* Chi, u16* Clo, int N) {
#pragma unroll
  for (int mi = 0; mi < 4; ++mi)
#pragma unroll
    for (int ni = 0; ni < 2; ++ni) {
      const int gcol = col0 + wc0 + ni * 16 + (lane & 15);
      const float b = HASBIAS ? bias[gcol] : 0.f;
#pragma unroll
      for (int r = 0; r < 4; ++r) {
        const int grow = row0 + wr0 + mi * 16 + (lane >> 4) * 4 + r;
        float v = acc[mi][ni][r] + b;
        if (RELU) v = fmaxf(v, 0.f);
        if (OUT_SPLIT) {
          const unsigned vh = rne_bits(v);
          Chi[(size_t)grow * N + gcol] = (u16)(vh >> 16);
          const float rr = v - __uint_as_float(vh & 0xFFFF0000u);
          Clo[(size_t)grow * N + gcol] = (u16)(rne_bits(rr) >> 16);
        } else {
          Cf[(size_t)grow * N + gcol] = v;
        }
      }
    }
}

// ---------------------------------------------------------------------------
// gemm_pipe3 (r10-proven): BM=128/BN=64/BK=32, 3 LDS buffers, counted vmcnt,
// raw s_barrier, T5 setprio around the MFMA cluster.
// ---------------------------------------------------------------------------
template<bool RELU, bool OUT_SPLIT, bool HASBIAS>
__device__ __forceinline__ void gemm_pipe3(
    int bx, int by,
    const u16* __restrict__ Ahi, const u16* __restrict__ Alo, int lda,
    const u16* __restrict__ Bthi, const u16* __restrict__ Btlo, int ldb,
    const float* __restrict__ bias,
    float* __restrict__ Cf, u16* __restrict__ Chi, u16* __restrict__ Clo,
    int N, int K, u16* lds) {
  const int tid = threadIdx.x;
  const int lane = tid & 63, wave = tid >> 6;
  const int row0 = by * 128, col0 = bx * 64;
  const int wr0 = (wave >> 1) * 64, wc0 = (wave & 1) * 32;
  const int srow = tid >> 2;
  const int sk   = ((tid & 3) ^ ((tid >> 3) & 3)) * 8;
  const int wu   = (tid & ~63) * 8;

  f32x4 acc[4][2];
#pragma unroll
  for (int mi = 0; mi < 4; ++mi)
#pragma unroll
    for (int ni = 0; ni < 2; ++ni) acc[mi][ni] = (f32x4){0.f, 0.f, 0.f, 0.f};

  auto stage = [&](int buf, int k0) {
    u16* base = lds + buf * 12288;
    gload16(Ahi + (size_t)(row0 + srow) * lda + k0 + sk,      base + wu);
    gload16(Ahi + (size_t)(row0 + 64 + srow) * lda + k0 + sk, base + 2048 + wu);
    gload16(Alo + (size_t)(row0 + srow) * lda + k0 + sk,      base + 4096 + wu);
    gload16(Alo + (size_t)(row0 + 64 + srow) * lda + k0 + sk, base + 6144 + wu);
    gload16(Bthi + (size_t)(col0 + srow) * ldb + k0 + sk, base + 8192 + wu);
    gload16(Btlo + (size_t)(col0 + srow) * ldb + k0 + sk, base + 10240 + wu);
  };
  auto compute = [&](int buf) {
    u16* base = lds + buf * 12288;
    const int ko_swz = ((lane >> 4) ^ ((lane >> 1) & 3)) * 8;
    const int ar = lane & 15;
    bf16x8 ah[4], al[4], bh[2], bl[2];
#pragma unroll
    for (int mi = 0; mi < 4; ++mi) {
      const int r = wr0 + mi * 16 + ar;
      ah[mi] = *(const bf16x8*)&base[r * 32 + ko_swz];
      al[mi] = *(const bf16x8*)&base[4096 + r * 32 + ko_swz];
    }
#pragma unroll
    for (int ni = 0; ni < 2; ++ni) {
      const int c = wc0 + ni * 16 + ar;
      bh[ni] = *(const bf16x8*)&base[8192 + c * 32 + ko_swz];
      bl[ni] = *(const bf16x8*)&base[10240 + c * 32 + ko_swz];
    }
    __builtin_amdgcn_s_setprio(1);
#pragma unroll
    for (int mi = 0; mi < 4; ++mi)
#pragma unroll
      for (int ni = 0; ni < 2; ++ni) {
        acc[mi][ni] = __builtin_amdgcn_mfma_f32_16x16x32_bf16(ah[mi], bh[ni], acc[mi][ni], 0, 0, 0);
        acc[mi][ni] = __builtin_amdgcn_mfma_f32_16x16x32_bf16(ah[mi], bl[ni], acc[mi][ni], 0, 0, 0);
        acc[mi][ni] = __builtin_amdgcn_mfma_f32_16x16x32_bf16(al[mi], bh[ni], acc[mi][ni], 0, 0, 0);
      }
    __builtin_amdgcn_s_setprio(0);
  };

  const int nk = K >> 5;
  stage(0, 0);
  stage(1, 32);
  int cb = 0;
  for (int k = 0; k < nk; ++k) {
    if (k + 2 < nk) {
      int sb = cb + 2; if (sb >= 3) sb -= 3;
      stage(sb, (k + 2) * 32);
      asm volatile("s_waitcnt vmcnt(12)" ::: "memory");
    } else if (k + 1 < nk) {
      asm volatile("s_waitcnt vmcnt(6)" ::: "memory");
    } else {
      asm volatile("s_waitcnt vmcnt(0)" ::: "memory");
    }
    __builtin_amdgcn_s_barrier();
    compute(cb);
    __builtin_amdgcn_s_barrier();
    ++cb; if (cb >= 3) cb -= 3;
  }

  epilogue_64<RELU, OUT_SPLIT, HASBIAS>(acc, row0, col0, wr0, wc0, lane,
                                        bias, Cf, Chi, Clo, N);
}

// ---------------------------------------------------------------------------
// gemm_a1p (r13-proven, Z1): fp32 A staged raw via gload16, register split,
// 3-buffer counted vmcnt, T5 setprio.
// ---------------------------------------------------------------------------
__device__ __forceinline__ void gemm_a1p(
    int bx, int by,
    const float* __restrict__ Aq, int lda,
    const u16* __restrict__ Bthi, const u16* __restrict__ Btlo, int ldb,
    float* __restrict__ Cf, int N, int K, u16* lds) {
  const int tid = threadIdx.x;
  const int lane = tid & 63, wave = tid >> 6;
  const int row0 = by * 128, col0 = bx * 64;
  const int wr0 = (wave >> 1) * 64, wc0 = (wave & 1) * 32;
  const int srow = tid >> 2;
  const int sk   = ((tid & 3) ^ ((tid >> 3) & 3)) * 8;
  const int wu   = (tid & ~63) * 8;
  const int arowA = tid >> 3;
  const int skA   = ((tid & 7) ^ ((tid >> 3) & 7)) * 4;  // fp32 units

  f32x4 acc[4][2];
#pragma unroll
  for (int mi = 0; mi < 4; ++mi)
#pragma unroll
    for (int ni = 0; ni < 2; ++ni) acc[mi][ni] = (f32x4){0.f, 0.f, 0.f, 0.f};

  auto stage = [&](int buf, int k0) {
    u16* base = lds + buf * 12288;
#pragma unroll
    for (int j = 0; j < 4; ++j) {
      gload16(Aq + (size_t)(row0 + 32 * j + arowA) * lda + k0 + skA,
              base + j * 2048 + wu);
    }
    gload16(Bthi + (size_t)(col0 + srow) * ldb + k0 + sk, base + 8192 + wu);
    gload16(Btlo + (size_t)(col0 + srow) * ldb + k0 + sk, base + 10240 + wu);
  };
  auto compute = [&](int buf) {
    u16* base = lds + buf * 12288;
    const float* Af = (const float*)base;
    const int ko_swz = ((lane >> 4) ^ ((lane >> 1) & 3)) * 8;
    const int c = lane >> 4;
    const int ar = lane & 15;
    bf16x8 ah[4], al[4], bh[2], bl[2];
#pragma unroll
    for (int mi = 0; mi < 4; ++mi) {
      const int r = wr0 + mi * 16 + ar;
      const int s = ar & 7;
      const f32x4 a0 = *(const f32x4*)&Af[r * 32 + (((2 * c) ^ s) * 4)];
      const f32x4 a1 = *(const f32x4*)&Af[r * 32 + (((2 * c + 1) ^ s) * 4)];
      const float xs[8] = {a0[0], a0[1], a0[2], a0[3], a1[0], a1[1], a1[2], a1[3]};
      union { u16 u[8]; bf16x8 v; } H, L;
#pragma unroll
      for (int e = 0; e < 8; ++e) {
        const unsigned vh = rne_bits(xs[e]);
        H.u[e] = (u16)(vh >> 16);
        const float rr = xs[e] - __uint_as_float(vh & 0xFFFF0000u);
        L.u[e] = (u16)(rne_bits(rr) >> 16);
      }
      ah[mi] = H.v; al[mi] = L.v;
    }
#pragma unroll
    for (int ni = 0; ni < 2; ++ni) {
      const int cc = wc0 + ni * 16 + ar;
      bh[ni] = *(const bf16x8*)&base[8192 + cc * 32 + ko_swz];
      bl[ni] = *(const bf16x8*)&base[10240 + cc * 32 + ko_swz];
    }
    __builtin_amdgcn_s_setprio(1);
#pragma unroll
    for (int mi = 0; mi < 4; ++mi)
#pragma unroll
      for (int ni = 0; ni < 2; ++ni) {
        acc[mi][ni] = __builtin_amdgcn_mfma_f32_16x16x32_bf16(ah[mi], bh[ni], acc[mi][ni], 0, 0, 0);
        acc[mi][ni] = __builtin_amdgcn_mfma_f32_16x16x32_bf16(ah[mi], bl[ni], acc[mi][ni], 0, 0, 0);
        acc[mi][ni] = __builtin_amdgcn_mfma_f32_16x16x32_bf16(al[mi], bh[ni], acc[mi][ni], 0, 0, 0);
      }
    __builtin_amdgcn_s_setprio(0);
  };

  const int nk = K >> 5;
  stage(0, 0);
  stage(1, 32);
  int cb = 0;
  for (int k = 0; k < nk; ++k) {
    if (k + 2 < nk) {
      int sb = cb + 2; if (sb >= 3) sb -= 3;
      stage(sb, (k + 2) * 32);
      asm volatile("s_waitcnt vmcnt(12)" ::: "memory");
    } else if (k + 1 < nk) {
      asm volatile("s_waitcnt vmcnt(6)" ::: "memory");
    } else {
      asm volatile("s_waitcnt vmcnt(0)" ::: "memory");
    }
    __builtin_amdgcn_s_barrier();
    compute(cb);
    __builtin_amdgcn_s_barrier();
    ++cb; if (cb >= 3) cb -= 3;
  }

  epilogue_64<false, false, false>(acc, row0, col0, wr0, wc0, lane,
                                   nullptr, Cf, nullptr, nullptr, N);
}

// ---------------------------------------------------------------------------
// gemm_pipe128 (r12-proven): BM=128/BN=128/BK=32, 2 LDS buffers, counted
// vmcnt(8), T5 setprio. Wave tile 64x64.
// ---------------------------------------------------------------------------
template<bool HASBIAS>
__device__ __forceinline__ void gemm_pipe128(
    int bx, int by,
    const u16* __restrict__ Ahi, const u16* __restrict__ Alo, int lda,
    const u16* __restrict__ Bthi, const u16* __restrict__ Btlo, int ldb,
    const float* __restrict__ bias, float* __restrict__ Cf,
    int N, int K, u16* lds) {
  const int tid = threadIdx.x;
  const int lane = tid & 63, wave = tid >> 6;
  const int row0 = by * 128, col0 = bx * 128;
  const int wr0 = (wave >> 1) * 64, wc0 = (wave & 1) * 64;
  const int srow = tid >> 2;
  const int sk   = ((tid & 3) ^ ((tid >> 3) & 3)) * 8;
  const int wu   = (tid & ~63) * 8;

  f32x4 acc[4][4];
#pragma unroll
  for (int mi = 0; mi < 4; ++mi)
#pragma unroll
    for (int ni = 0; ni < 4; ++ni) acc[mi][ni] = (f32x4){0.f, 0.f, 0.f, 0.f};

  auto stage = [&](int buf, int k0) {
    u16* base = lds + buf * 16384;
    gload16(Ahi + (size_t)(row0 + srow) * lda + k0 + sk,      base + wu);
    gload16(Ahi + (size_t)(row0 + 64 + srow) * lda + k0 + sk, base + 2048 + wu);
    gload16(Alo + (size_t)(row0 + srow) * lda + k0 + sk,      base + 4096 + wu);
    gload16(Alo + (size_t)(row0 + 64 + srow) * lda + k0 + sk, base + 6144 + wu);
    gload16(Bthi + (size_t)(col0 + srow) * ldb + k0 + sk,      base + 8192 + wu);
    gload16(Bthi + (size_t)(col0 + 64 + srow) * ldb + k0 + sk, base + 10240 + wu);
    gload16(Btlo + (size_t)(col0 + srow) * ldb + k0 + sk,      base + 12288 + wu);
    gload16(Btlo + (size_t)(col0 + 64 + srow) * ldb + k0 + sk, base + 14336 + wu);
  };
  auto compute = [&](int buf) {
    u16* base = lds + buf * 16384;
    const int ko_swz = ((lane >> 4) ^ ((lane >> 1) & 3)) * 8;
    const int ar = lane & 15;
    bf16x8 ah[4], al[4], bh[4], bl[4];
#pragma unroll
    for (int mi = 0; mi < 4; ++mi) {
      const int r = wr0 + mi * 16 + ar;
      ah[mi] = *(const bf16x8*)&base[r * 32 + ko_swz];
      al[mi] = *(const bf16x8*)&base[4096 + r * 32 + ko_swz];
    }
#pragma unroll
    for (int ni = 0; ni < 4; ++ni) {
      const int c = wc0 + ni * 16 + ar;
      bh[ni] = *(const bf16x8*)&base[8192 + c * 32 + ko_swz];
      bl[ni] = *(const bf16x8*)&base[12288 + c * 32 + ko_swz];
    }
    __builtin_amdgcn_s_setprio(1);
#pragma unroll
    for (int mi = 0; mi < 4; ++mi)
#pragma unroll
      for (int ni = 0; ni < 4; ++ni) {
        acc[mi][ni] = __builtin_amdgcn_mfma_f32_16x16x32_bf16(ah[mi], bh[ni], acc[mi][ni], 0, 0, 0);
        acc[mi][ni] = __builtin_amdgcn_mfma_f32_16x16x32_bf16(ah[mi], bl[ni], acc[mi][ni], 0, 0, 0);
        acc[mi][ni] = __builtin_amdgcn_mfma_f32_16x16x32_bf16(al[mi], bh[ni], acc[mi][ni], 0, 0, 0);
      }
    __builtin_amdgcn_s_setprio(0);
  };

  const int nk = K >> 5;
  stage(0, 0);
  int cur = 0;
  for (int k = 0; k < nk; ++k) {
    if (k + 1 < nk) {
      stage(cur ^ 1, (k + 1) * 32);
      asm volatile("s_waitcnt vmcnt(8)" ::: "memory");
    } else {
      asm volatile("s_waitcnt vmcnt(0)" ::: "memory");
    }
    __builtin_amdgcn_s_barrier();
    compute(cur);
    __builtin_amdgcn_s_barrier();
    cur ^= 1;
  }

#pragma unroll
  for (int mi = 0; mi < 4; ++mi)
#pragma unroll
    for (int ni = 0; ni < 4; ++ni) {
      const int gcol = col0 + wc0 + ni * 16 + (lane & 15);
      const float b = HASBIAS ? bias[gcol] : 0.f;
#pragma unroll
      for (int r = 0; r < 4; ++r) {
        const int grow = row0 + wr0 + mi * 16 + (lane >> 4) * 4 + r;
        Cf[(size_t)grow * N + gcol] = acc[mi][ni][r] + b;
      }
    }
}

// GEMM1: 512 linear blocks, XCD-banded (r14-proven).
__global__ __launch_bounds__(256, 2) void gemm1_kernel(
    const u16* __restrict__ a_hi, const u16* __restrict__ a_lo,
    const u16* __restrict__ w1t_hi, const u16* __restrict__ w1t_lo,
    const float* __restrict__ b1,
    u16* __restrict__ h_hi, u16* __restrict__ h_lo) {
  __shared__ u16 lds[3 * 12288];
  const int r = blockIdx.x;              // 0..511
  const int x = r & 7;                   // XCD (dispatch round-robin)
  const int i = r >> 3;                  // 0..63 within XCD
  const int by = x * 4 + (i >> 4);       // 4 row-bands per XCD
  const int bx = i & 15;
  gemm_pipe3<true, true, true>(bx, by,
      a_hi, a_lo, K1PAD, w1t_hi, w1t_lo, K1PAD, b1,
      nullptr, h_hi, h_lo, HMLP, K1PAD, lds);
}

// Fused: Z1 (128 a1p blocks, same-band-same-XCD) + adj (1024 XCD-chunked)
__global__ __launch_bounds__(256, 2) void fused2_kernel(
    const u16* __restrict__ h_hi, const u16* __restrict__ h_lo,
    const u16* __restrict__ w2t_hi, const u16* __restrict__ w2t_lo,
    const float* __restrict__ b2, float* __restrict__ adj,
    const float* __restrict__ node,
    const u16* __restrict__ w1ct_hi, const u16* __restrict__ w1ct_lo,
    float* __restrict__ Z1) {
  __shared__ u16 lds[3 * 12288];          // 72 KB (a1p); pipe128 uses 64 KB
  const int bid = blockIdx.x;
  if (bid < 128) {          // Z1 = node @ conv_w1 (fp32 out, no bias)
    const int x = bid & 7;                // XCD
    const int i = bid >> 3;               // 0..15 within XCD
    const int by = x * 4 + (i >> 2);      // 4 bands per XCD
    const int bx = i & 3;
    gemm_a1p(bx, by,
             node, D_DIM, w1ct_hi, w1ct_lo, D_DIM,
             Z1, 256, D_DIM, lds);
  } else {                  // adj = h @ W2 + b2; XCD-chunked (r13-proven)
    const int r = bid - 128;              // 1024 blocks; (r+128)%8 == r%8
    const int x = r & 7;
    const int i = r >> 3;
    const int by = x * 4 + (i >> 5);
    const int bx = i & 31;
    gemm_pipe128<true>(bx, by,
        h_hi, h_lo, HMLP, w2t_hi, w2t_lo, HMLP, b2,
        adj, N_NODES, HMLP, lds);
  }
}

// ---------------------------------------------------------------------------
// Small fp32 GEMM (Z2 only): 64x64 tile, BK=16, 256 threads, 4x4/thread.
// ---------------------------------------------------------------------------
__global__ __launch_bounds__(256) void gemm_small(
    const float* __restrict__ A, const float* __restrict__ B,
    float* __restrict__ C, int M, int Ncols, int K) {
  __shared__ float As[16][68];
  __shared__ float Bs[16][68];
  const int tid = threadIdx.x;
  const int row0 = blockIdx.y * 64, col0 = blockIdx.x * 64;
  const int tx = tid & 15, ty = tid >> 4;
  const int arow = tid >> 2, acol = (tid & 3) * 4;
  const int brow = tid >> 4, bcol = (tid & 15) * 4;

  float acc[4][4];
#pragma unroll
  for (int i = 0; i < 4; ++i)
#pragma unroll
    for (int j = 0; j < 4; ++j) acc[i][j] = 0.f;

  for (int k0 = 0; k0 < K; k0 += 16) {
    const float4 a4 = *(const float4*)(A + (size_t)(row0 + arow) * K + k0 + acol);
    const float4 b4 = *(const float4*)(B + (size_t)(k0 + brow) * Ncols + col0 + bcol);
    __syncthreads();
    As[acol + 0][arow] = a4.x; As[acol + 1][arow] = a4.y;
    As[acol + 2][arow] = a4.z; As[acol + 3][arow] = a4.w;
    *(float4*)&Bs[brow][bcol] = b4;
    __syncthreads();
#pragma unroll
    for (int k = 0; k < 16; ++k) {
      float av[4], bw[4];
      *(float4*)&av[0] = *(const float4*)&As[k][ty * 4];
      *(float4*)&bw[0] = *(const float4*)&Bs[k][tx * 4];
#pragma unroll
      for (int i = 0; i < 4; ++i)
#pragma unroll
        for (int j = 0; j < 4; ++j) acc[i][j] += av[i] * bw[j];
    }
  }

#pragma unroll
  for (int i = 0; i < 4; ++i) {
    const int r = row0 + ty * 4 + i;
    float4 v;
    v.x = acc[i][0]; v.y = acc[i][1]; v.z = acc[i][2]; v.w = acc[i][3];
    *(float4*)(C + (size_t)r * Ncols + col0 + tx * 4) = v;
  }
}

// ---------------------------------------------------------------------------
// Top-K: one block/row; per-thread cached argmax + shfl_xor butterfly;
// only the winner thread rescans its 16 elements. Tie -> lowest index.
// ---------------------------------------------------------------------------
__global__ __launch_bounds__(256) void topk_kernel(
    const float* __restrict__ adj, float* __restrict__ vals,
    int* __restrict__ idxo, float* __restrict__ dinv) {
  __shared__ float sv[N_NODES];
  __shared__ float rw[4];
  __shared__ int   iw[4];
  const int n = blockIdx.x, tid = threadIdx.x;
  const int lane = tid & 63, wave = tid >> 6;
  const float4* rowp = (const float4*)(adj + (size_t)n * N_NODES);

  float mv = -FLT_MAX; int mi = 0x7FFFFFFF;
  for (int g = tid; g < N_NODES / 4; g += 256) {
    const float4 v4 = rowp[g];
    *(float4*)&sv[g * 4] = v4;
    if (v4.x > mv) { mv = v4.x; mi = g * 4 + 0; }
    if (v4.y > mv) { mv = v4.y; mi = g * 4 + 1; }
    if (v4.z > mv) { mv = v4.z; mi = g * 4 + 2; }
    if (v4.w > mv) { mv = v4.w; mi = g * 4 + 3; }
  }

  float sum = 0.f;
  for (int it = 0; it < TOPK; ++it) {
    float bv = mv; int bi = mi;
#pragma unroll
    for (int off = 1; off < 64; off <<= 1) {
      const float ov = __shfl_xor(bv, off);
      const int   oi = __shfl_xor(bi, off);
      if (ov > bv || (ov == bv && oi < bi)) { bv = ov; bi = oi; }
    }
    if (lane == 0) { rw[wave] = bv; iw[wave] = bi; }
    __syncthreads();
    bv = rw[0]; bi = iw[0];
#pragma unroll
    for (int w = 1; w < 4; ++w) {
      const float ov = rw[w]; const int oi = iw[w];
      if (ov > bv || (ov == bv && oi < bi)) { bv = ov; bi = oi; }
    }
    if (tid == 0) {
      vals[(size_t)n * TOPK + it] = bv;
      idxo[(size_t)n * TOPK + it] = bi;
    }
    sum += bv;
    if (tid == ((bi >> 2) & 255)) {        // owner removes + rescans its 16
      sv[bi] = -FLT_MAX;
      mv = -FLT_MAX; mi = 0x7FFFFFFF;
      for (int g = tid; g < N_NODES / 4; g += 256) {
#pragma unroll
        for (int e = 0; e < 4; ++e) {
          const float v = sv[g * 4 + e];
          if (v > mv) { mv = v; mi = g * 4 + e; }
        }
      }
    }
    __syncthreads();
  }
  if (tid == 0)
    dinv[n] = (sum > 0.f) ? rsqrtf(fmaxf(sum, 1e-12f)) : 0.f;
}

// out[n,f] = bias[f] + sum_k vals[n,k]*dinv[n]*dinv[idx]*Z[idx[n,k], f]
__global__ __launch_bounds__(256) void agg_kernel(
    const float* __restrict__ Z, const float* __restrict__ vals,
    const int* __restrict__ idxo, const float* __restrict__ dinv,
    const float* __restrict__ bias, float* __restrict__ out) {
  const int n = blockIdx.x, f = threadIdx.x;
  const float dn = dinv[n];
  float acc = bias[f];
#pragma unroll
  for (int k = 0; k < TOPK; ++k) {
    const int   j = idxo[n * TOPK + k];
    const float w = vals[n * TOPK + k] * dn * dinv[j];
    acc += w * Z[(size_t)j * 256 + f];
  }
  out[(size_t)n * 256 + f] = acc;
}

// BatchNorm stats: 128 partial slabs of 32 rows, then tree reduce.
__global__ __launch_bounds__(256) void bn_partial(
    const float* __restrict__ x, float* __restrict__ partial) {
  const int b = blockIdx.x, c = threadIdx.x;
  float s = 0.f, s2 = 0.f;
  for (int r = b * 32; r < b * 32 + 32; ++r) {
    const float v = x[(size_t)r * 256 + c];
    s += v; s2 += v * v;
  }
  partial[(size_t)b * 512 + c]       = s;
  partial[(size_t)b * 512 + 256 + c] = s2;
}

__global__ __launch_bounds__(256) void bn_reduce(
    const float* __restrict__ partial, float* __restrict__ colstats) {
  const int j = blockIdx.x, t = threadIdx.x;
  __shared__ float red[128];
  if (t < 128) red[t] = partial[(size_t)t * 512 + j];
  __syncthreads();
  for (int s = 64; s > 0; s >>= 1) {
    if (t < s) red[t] += red[t + s];
    __syncthreads();
  }
  if (t == 0) colstats[j] = red[0];
}

__global__ __launch_bounds__(256) void bn_apply(
    float* __restrict__ x, const float* __restrict__ colstats,
    const float* __restrict__ gamma, const float* __restrict__ beta) {
  const int i = blockIdx.x * 256 + threadIdx.x;
  const int c = i & 255;
  const float mean = colstats[c] * (1.f / 4096.f);
  float var = colstats[256 + c] * (1.f / 4096.f) - mean * mean;
  var = fmaxf(var, 0.f);
  const float v = (x[i] - mean) * rsqrtf(var + 1e-5f) * gamma[c] + beta[c];
  x[i] = fmaxf(v, 0.f);
}

// ---------------------------------------------------------------------------
extern "C" void kernel_launch(void* const* d_in, const int* in_sizes, int n_in,
                              void* d_out, int out_size, void* d_ws, size_t ws_size,
                              hipStream_t stream) {
  const float* probs   = (const float*)d_in[0];
  const float* bbox    = (const float*)d_in[1];
  const float* query   = (const float*)d_in[2];
  const float* node    = (const float*)d_in[3];
  const float* mlp_w1  = (const float*)d_in[4];
  const float* mlp_b1  = (const float*)d_in[5];
  const float* mlp_w2  = (const float*)d_in[6];
  const float* mlp_b2  = (const float*)d_in[7];
  const float* conv_w1 = (const float*)d_in[8];
  const float* conv_b1 = (const float*)d_in[9];
  const float* conv_w2 = (const float*)d_in[10];
  const float* conv_b2 = (const float*)d_in[11];
  const float* gamma   = (const float*)d_in[12];
  const float* beta    = (const float*)d_in[13];

  // --- workspace layout (peak 30,408,704 floats = 121.6 MB; r2 proved 123.2) ---
  float* ws = (float*)d_ws;
  size_t off = 0;
  // R1: a planes [4096][5120] u16 x2 during gemm1; adj + spare afterwards
  float* R1 = ws + off;  off += (size_t)N_NODES * K1PAD;         // 20,971,520 f
  u16* a_hi = (u16*)R1;
  u16* a_lo = a_hi + (size_t)N_NODES * K1PAD;
  float* adj = R1;                                               // 16,777,216 f
  float* spare = R1 + (size_t)N_NODES * N_NODES;                 //  4,194,304 f
  float* Z1   = spare;
  float* vals = spare + (size_t)N_NODES * 256;
  int*   idxo = (int*)(vals + (size_t)N_NODES * TOPK);
  float* dinv = (float*)idxo + (size_t)N_NODES * TOPK;
  float* partial  = dinv + N_NODES;
  float* colstats = partial + 128 * 512;
  // R2: w1t during gemm1; w2t + w1ct afterwards; out1 overlays w1ct
  float* R2 = ws + off;  off += (size_t)HMLP * K1PAD;            //  5,242,880 f
  u16* w1t_hi = (u16*)R2;
  u16* w1t_lo = w1t_hi + (size_t)HMLP * K1PAD;
  u16* w2t_hi = (u16*)R2;
  u16* w2t_lo = w2t_hi + (size_t)N_NODES * HMLP;
  u16* w1ct_hi = (u16*)(R2 + (size_t)N_NODES * HMLP);
  u16* w1ct_lo = w1ct_hi + (size_t)256 * D_DIM;
  float* out1 = R2 + (size_t)N_NODES * HMLP;                     // post-fused2
  // R3: h planes
  float* R3 = ws + off;  off += (size_t)N_NODES * HMLP;          //  4,194,304 f
  u16* h_hi = (u16*)R3;
  u16* h_lo = h_hi + (size_t)N_NODES * HMLP;
  float* Z2 = adj;                       // adj dead after topk

  // 1) a planes = split([query | probs | bbox | 0])     [4096][5120]
  a_split<<<(N_NODES * K1PAD) / (256 * 8), 256, 0, stream>>>(
      query, probs, bbox, a_hi, a_lo);
  // 2) W1t hi/lo = split-transpose(mlp_w1)              [1024][5120]
  transpose_split<<<dim3(K1PAD / 64, HMLP / 64), 256, 0, stream>>>(
      mlp_w1, KCAT, HMLP, K1PAD, w1t_hi, w1t_lo);
  // 3) h = relu(Apad @ W1 + b1) -> bf16 hi/lo           (4096 x 1024)
  gemm1_kernel<<<512, 256, 0, stream>>>(
      a_hi, a_lo, w1t_hi, w1t_lo, mlp_b1, h_hi, h_lo);
  // 4) W2t hi/lo = split-transpose(mlp_w2)              [4096][1024]
  transpose_split<<<dim3(HMLP / 64, N_NODES / 64), 256, 0, stream>>>(
      mlp_w2, HMLP, N_NODES, HMLP, w2t_hi, w2t_lo);
  // 5) W1Ct hi/lo = split-transpose(conv_w1)            [256][4096]
  transpose_split<<<dim3(D_DIM / 64, 256 / 64), 256, 0, stream>>>(
      conv_w1, D_DIM, 256, D_DIM, w1ct_hi, w1ct_lo);
  // 6) fused: Z1 (128 blocks, band-local) + adj (1024 XCD-chunked blocks)
  fused2_kernel<<<128 + (N_NODES / 128) * (N_NODES / 128), 256, 0, stream>>>(
      h_hi, h_lo, w2t_hi, w2t_lo, mlp_b2, adj, node, w1ct_hi, w1ct_lo, Z1);
  // 7) top-32 per row + dinv
  topk_kernel<<<N_NODES, 256, 0, stream>>>(adj, vals, idxo, dinv);
  // 8) out1 = gather-agg(Z1) + conv_b1
  agg_kernel<<<N_NODES, 256, 0, stream>>>(Z1, vals, idxo, dinv, conv_b1, out1);
  // 9) BatchNorm (batch stats) + relu, in place
  bn_partial<<<128, 256, 0, stream>>>(out1, partial);
  bn_reduce<<<512, 256, 0, stream>>>(partial, colstats);
  bn_apply<<<N_NODES, 256, 0, stream>>>(out1, colstats, gamma, beta);
  // 10) Z2 = y @ conv_w2 (fp32)                         (4096 x 256)
  gemm_small<<<dim3(256 / 64, N_NODES / 64), 256, 0, stream>>>(
      out1, conv_w2, Z2, N_NODES, 256, 256);
  // 11) out = gather-agg(Z2) + conv_b2
  agg_kernel<<<N_NODES, 256, 0, stream>>>(Z2, vals, idxo, dinv, conv_b2, (float*)d_out);
}

// Round 17
// 536.641 us; speedup vs baseline: 1.0263x; 1.0263x over previous
//
#include <hip/hip_runtime.h>
#include <cfloat>

#define N_NODES 4096
#define C1_DIM  1001
#define D_DIM   4096
#define HMLP    1024
#define KCAT    (D_DIM + C1_DIM + 4)   // 5101
#define K1PAD   5120                   // padded, multiple of 32
#define TOPK    32

typedef unsigned short u16;
typedef __bf16 bf16x8 __attribute__((ext_vector_type(8)));
typedef float  f32x4  __attribute__((ext_vector_type(4)));

// RNE round-to-bf16 (round-4-proven numerics).
__device__ __forceinline__ unsigned rne_bits(float x) {
  const unsigned u = __float_as_uint(x);
  return u + 0x7FFFu + ((u >> 16) & 1u);
}

__device__ __forceinline__ void gload16(const void* g, void* l) {
  __builtin_amdgcn_global_load_lds(
      (const __attribute__((address_space(1))) unsigned int*)g,
      (__attribute__((address_space(3))) unsigned int*)l, 16, 0, 0);
}

// ---------------------------------------------------------------------------
// a_split: build a_hi/a_lo [4096][5120] planes in one pass.
// ---------------------------------------------------------------------------
__global__ __launch_bounds__(256) void a_split(
    const float* __restrict__ query, const float* __restrict__ probs,
    const float* __restrict__ bbox,
    u16* __restrict__ hi, u16* __restrict__ lo) {
  const size_t idx = ((size_t)blockIdx.x * 256 + threadIdx.x) * 8;
  const int row = (int)(idx / K1PAD);
  const int col = (int)(idx - (size_t)row * K1PAD);
  float xs[8];
  if (col < D_DIM) {
    const float4 x0 = *(const float4*)(query + (size_t)row * D_DIM + col);
    const float4 x1 = *(const float4*)(query + (size_t)row * D_DIM + col + 4);
    xs[0]=x0.x; xs[1]=x0.y; xs[2]=x0.z; xs[3]=x0.w;
    xs[4]=x1.x; xs[5]=x1.y; xs[6]=x1.z; xs[7]=x1.w;
  } else {
#pragma unroll
    for (int e = 0; e < 8; ++e) {
      const int c = col + e - D_DIM;
      xs[e] = (c < C1_DIM) ? probs[(size_t)row * C1_DIM + c]
            : (c < C1_DIM + 4) ? bbox[(size_t)row * 4 + (c - C1_DIM)] : 0.f;
    }
  }
  unsigned hw[4], lw[4];
#pragma unroll
  for (int p = 0; p < 4; ++p) {
    const unsigned v0 = rne_bits(xs[2*p]);
    const unsigned v1 = rne_bits(xs[2*p+1]);
    hw[p] = (v1 & 0xFFFF0000u) | (v0 >> 16);
    const float r0 = xs[2*p]   - __uint_as_float(v0 & 0xFFFF0000u);
    const float r1 = xs[2*p+1] - __uint_as_float(v1 & 0xFFFF0000u);
    lw[p] = (rne_bits(r1) & 0xFFFF0000u) | (rne_bits(r0) >> 16);
  }
  *(uint4*)(hi + idx) = make_uint4(hw[0], hw[1], hw[2], hw[3]);
  *(uint4*)(lo + idx) = make_uint4(lw[0], lw[1], lw[2], lw[3]);
}

// ---------------------------------------------------------------------------
// out_hi/lo[C][Rpad] = split-bf16 (RNE) transpose of in[R][C] (zero pad r>=R)
// ---------------------------------------------------------------------------
__global__ __launch_bounds__(256) void transpose_split(
    const float* __restrict__ in, int R, int C, int Rpad,
    u16* __restrict__ out_hi, u16* __restrict__ out_lo) {
  __shared__ float t[64][65];
  const int rb = blockIdx.x * 64;
  const int cb = blockIdx.y * 64;
  const int tid = threadIdx.x;
  const int lr = tid >> 6, lc = tid & 63;
#pragma unroll
  for (int i = 0; i < 16; ++i) {
    const int r = lr + i * 4;
    const int gr = rb + r;
    t[r][lc] = (gr < R) ? in[(size_t)gr * C + cb + lc] : 0.f;
  }
  __syncthreads();
#pragma unroll
  for (int i = 0; i < 16; ++i) {
    const int c = lr + i * 4;
    const float v = t[lc][c];
    const unsigned vh = rne_bits(v);
    const float r = v - __uint_as_float(vh & 0xFFFF0000u);
    const size_t o = (size_t)(cb + c) * Rpad + rb + lc;
    out_hi[o] = (u16)(vh >> 16);
    out_lo[o] = (u16)(rne_bits(r) >> 16);
  }
}

// ===========================================================================
// u16-plane swizzle (r9-proven, 0 conflicts): stored 16B-chunk =
// logical ^ ((row>>1)&3); gload SOURCE pre-swizzled (sk), LDS dest linear;
// reads use ko_swz. fp32-A swizzle (Z1): stored = logical ^ (row&7).
// ===========================================================================

template<bool RELU, bool OUT_SPLIT, bool HASBIAS>
__device__ __forceinline__ void epilogue_64(
    f32x4 (&acc)[4][2], int row0, int col0, int wr0, int wc0, int lane,
    const float* bias, float* Cf, u16* Chi, u16* Clo, int N) {
#pragma unroll
  for (int mi = 0; mi < 4; ++mi)
#pragma unroll
    for (int ni = 0; ni < 2; ++ni) {
      const int gcol = col0 + wc0 + ni * 16 + (lane & 15);
      const float b = HASBIAS ? bias[gcol] : 0.f;
#pragma unroll
      for (int r = 0; r < 4; ++r) {
        const int grow = row0 + wr0 + mi * 16 + (lane >> 4) * 4 + r;
        float v = acc[mi][ni][r] + b;
        if (RELU) v = fmaxf(v, 0.f);
        if (OUT_SPLIT) {
          const unsigned vh = rne_bits(v);
          Chi[(size_t)grow * N + gcol] = (u16)(vh >> 16);
          const float rr = v - __uint_as_float(vh & 0xFFFF0000u);
          Clo[(size_t)grow * N + gcol] = (u16)(rne_bits(rr) >> 16);
        } else {
          Cf[(size_t)grow * N + gcol] = v;
        }
      }
    }
}

// ---------------------------------------------------------------------------
// gemm_pipe3 (r10-proven): BM=128/BN=64/BK=32, 3 LDS buffers, counted vmcnt,
// raw s_barrier. (setprio reverted: null on this lockstep structure, r16.)
// ---------------------------------------------------------------------------
template<bool RELU, bool OUT_SPLIT, bool HASBIAS>
__device__ __forceinline__ void gemm_pipe3(
    int bx, int by,
    const u16* __restrict__ Ahi, const u16* __restrict__ Alo, int lda,
    const u16* __restrict__ Bthi, const u16* __restrict__ Btlo, int ldb,
    const float* __restrict__ bias,
    float* __restrict__ Cf, u16* __restrict__ Chi, u16* __restrict__ Clo,
    int N, int K, u16* lds) {
  const int tid = threadIdx.x;
  const int lane = tid & 63, wave = tid >> 6;
  const int row0 = by * 128, col0 = bx * 64;
  const int wr0 = (wave >> 1) * 64, wc0 = (wave & 1) * 32;
  const int srow = tid >> 2;
  const int sk   = ((tid & 3) ^ ((tid >> 3) & 3)) * 8;
  const int wu   = (tid & ~63) * 8;

  f32x4 acc[4][2];
#pragma unroll
  for (int mi = 0; mi < 4; ++mi)
#pragma unroll
    for (int ni = 0; ni < 2; ++ni) acc[mi][ni] = (f32x4){0.f, 0.f, 0.f, 0.f};

  auto stage = [&](int buf, int k0) {
    u16* base = lds + buf * 12288;
    gload16(Ahi + (size_t)(row0 + srow) * lda + k0 + sk,      base + wu);
    gload16(Ahi + (size_t)(row0 + 64 + srow) * lda + k0 + sk, base + 2048 + wu);
    gload16(Alo + (size_t)(row0 + srow) * lda + k0 + sk,      base + 4096 + wu);
    gload16(Alo + (size_t)(row0 + 64 + srow) * lda + k0 + sk, base + 6144 + wu);
    gload16(Bthi + (size_t)(col0 + srow) * ldb + k0 + sk, base + 8192 + wu);
    gload16(Btlo + (size_t)(col0 + srow) * ldb + k0 + sk, base + 10240 + wu);
  };
  auto compute = [&](int buf) {
    u16* base = lds + buf * 12288;
    const int ko_swz = ((lane >> 4) ^ ((lane >> 1) & 3)) * 8;
    const int ar = lane & 15;
    bf16x8 ah[4], al[4], bh[2], bl[2];
#pragma unroll
    for (int mi = 0; mi < 4; ++mi) {
      const int r = wr0 + mi * 16 + ar;
      ah[mi] = *(const bf16x8*)&base[r * 32 + ko_swz];
      al[mi] = *(const bf16x8*)&base[4096 + r * 32 + ko_swz];
    }
#pragma unroll
    for (int ni = 0; ni < 2; ++ni) {
      const int c = wc0 + ni * 16 + ar;
      bh[ni] = *(const bf16x8*)&base[8192 + c * 32 + ko_swz];
      bl[ni] = *(const bf16x8*)&base[10240 + c * 32 + ko_swz];
    }
#pragma unroll
    for (int mi = 0; mi < 4; ++mi)
#pragma unroll
      for (int ni = 0; ni < 2; ++ni) {
        acc[mi][ni] = __builtin_amdgcn_mfma_f32_16x16x32_bf16(ah[mi], bh[ni], acc[mi][ni], 0, 0, 0);
        acc[mi][ni] = __builtin_amdgcn_mfma_f32_16x16x32_bf16(ah[mi], bl[ni], acc[mi][ni], 0, 0, 0);
        acc[mi][ni] = __builtin_amdgcn_mfma_f32_16x16x32_bf16(al[mi], bh[ni], acc[mi][ni], 0, 0, 0);
      }
  };

  const int nk = K >> 5;
  stage(0, 0);
  stage(1, 32);
  int cb = 0;
  for (int k = 0; k < nk; ++k) {
    if (k + 2 < nk) {
      int sb = cb + 2; if (sb >= 3) sb -= 3;
      stage(sb, (k + 2) * 32);
      asm volatile("s_waitcnt vmcnt(12)" ::: "memory");
    } else if (k + 1 < nk) {
      asm volatile("s_waitcnt vmcnt(6)" ::: "memory");
    } else {
      asm volatile("s_waitcnt vmcnt(0)" ::: "memory");
    }
    __builtin_amdgcn_s_barrier();
    compute(cb);
    __builtin_amdgcn_s_barrier();
    ++cb; if (cb >= 3) cb -= 3;
  }

  epilogue_64<RELU, OUT_SPLIT, HASBIAS>(acc, row0, col0, wr0, wc0, lane,
                                        bias, Cf, Chi, Clo, N);
}

// ---------------------------------------------------------------------------
// gemm_a1p (r13-proven, Z1): fp32 A staged raw via gload16, register split,
// 3-buffer counted vmcnt.
// ---------------------------------------------------------------------------
__device__ __forceinline__ void gemm_a1p(
    int bx, int by,
    const float* __restrict__ Aq, int lda,
    const u16* __restrict__ Bthi, const u16* __restrict__ Btlo, int ldb,
    float* __restrict__ Cf, int N, int K, u16* lds) {
  const int tid = threadIdx.x;
  const int lane = tid & 63, wave = tid >> 6;
  const int row0 = by * 128, col0 = bx * 64;
  const int wr0 = (wave >> 1) * 64, wc0 = (wave & 1) * 32;
  const int srow = tid >> 2;
  const int sk   = ((tid & 3) ^ ((tid >> 3) & 3)) * 8;
  const int wu   = (tid & ~63) * 8;
  const int arowA = tid >> 3;
  const int skA   = ((tid & 7) ^ ((tid >> 3) & 7)) * 4;  // fp32 units

  f32x4 acc[4][2];
#pragma unroll
  for (int mi = 0; mi < 4; ++mi)
#pragma unroll
    for (int ni = 0; ni < 2; ++ni) acc[mi][ni] = (f32x4){0.f, 0.f, 0.f, 0.f};

  auto stage = [&](int buf, int k0) {
    u16* base = lds + buf * 12288;
#pragma unroll
    for (int j = 0; j < 4; ++j) {
      gload16(Aq + (size_t)(row0 + 32 * j + arowA) * lda + k0 + skA,
              base + j * 2048 + wu);
    }
    gload16(Bthi + (size_t)(col0 + srow) * ldb + k0 + sk, base + 8192 + wu);
    gload16(Btlo + (size_t)(col0 + srow) * ldb + k0 + sk, base + 10240 + wu);
  };
  auto compute = [&](int buf) {
    u16* base = lds + buf * 12288;
    const float* Af = (const float*)base;
    const int ko_swz = ((lane >> 4) ^ ((lane >> 1) & 3)) * 8;
    const int c = lane >> 4;
    const int ar = lane & 15;
    bf16x8 ah[4], al[4], bh[2], bl[2];
#pragma unroll
    for (int mi = 0; mi < 4; ++mi) {
      const int r = wr0 + mi * 16 + ar;
      const int s = ar & 7;
      const f32x4 a0 = *(const f32x4*)&Af[r * 32 + (((2 * c) ^ s) * 4)];
      const f32x4 a1 = *(const f32x4*)&Af[r * 32 + (((2 * c + 1) ^ s) * 4)];
      const float xs[8] = {a0[0], a0[1], a0[2], a0[3], a1[0], a1[1], a1[2], a1[3]};
      union { u16 u[8]; bf16x8 v; } H, L;
#pragma unroll
      for (int e = 0; e < 8; ++e) {
        const unsigned vh = rne_bits(xs[e]);
        H.u[e] = (u16)(vh >> 16);
        const float rr = xs[e] - __uint_as_float(vh & 0xFFFF0000u);
        L.u[e] = (u16)(rne_bits(rr) >> 16);
      }
      ah[mi] = H.v; al[mi] = L.v;
    }
#pragma unroll
    for (int ni = 0; ni < 2; ++ni) {
      const int cc = wc0 + ni * 16 + ar;
      bh[ni] = *(const bf16x8*)&base[8192 + cc * 32 + ko_swz];
      bl[ni] = *(const bf16x8*)&base[10240 + cc * 32 + ko_swz];
    }
#pragma unroll
    for (int mi = 0; mi < 4; ++mi)
#pragma unroll
      for (int ni = 0; ni < 2; ++ni) {
        acc[mi][ni] = __builtin_amdgcn_mfma_f32_16x16x32_bf16(ah[mi], bh[ni], acc[mi][ni], 0, 0, 0);
        acc[mi][ni] = __builtin_amdgcn_mfma_f32_16x16x32_bf16(ah[mi], bl[ni], acc[mi][ni], 0, 0, 0);
        acc[mi][ni] = __builtin_amdgcn_mfma_f32_16x16x32_bf16(al[mi], bh[ni], acc[mi][ni], 0, 0, 0);
      }
  };

  const int nk = K >> 5;
  stage(0, 0);
  stage(1, 32);
  int cb = 0;
  for (int k = 0; k < nk; ++k) {
    if (k + 2 < nk) {
      int sb = cb + 2; if (sb >= 3) sb -= 3;
      stage(sb, (k + 2) * 32);
      asm volatile("s_waitcnt vmcnt(12)" ::: "memory");
    } else if (k + 1 < nk) {
      asm volatile("s_waitcnt vmcnt(6)" ::: "memory");
    } else {
      asm volatile("s_waitcnt vmcnt(0)" ::: "memory");
    }
    __builtin_amdgcn_s_barrier();
    compute(cb);
    __builtin_amdgcn_s_barrier();
    ++cb; if (cb >= 3) cb -= 3;
  }

  epilogue_64<false, false, false>(acc, row0, col0, wr0, wc0, lane,
                                   nullptr, Cf, nullptr, nullptr, N);
}

// ---------------------------------------------------------------------------
// gemm_pipe128 (r12-proven): BM=128/BN=128/BK=32, 2 LDS buffers, counted
// vmcnt(8). Wave tile 64x64.
// ---------------------------------------------------------------------------
template<bool HASBIAS>
__device__ __forceinline__ void gemm_pipe128(
    int bx, int by,
    const u16* __restrict__ Ahi, const u16* __restrict__ Alo, int lda,
    const u16* __restrict__ Bthi, const u16* __restrict__ Btlo, int ldb,
    const float* __restrict__ bias, float* __restrict__ Cf,
    int N, int K, u16* lds) {
  const int tid = threadIdx.x;
  const int lane = tid & 63, wave = tid >> 6;
  const int row0 = by * 128, col0 = bx * 128;
  const int wr0 = (wave >> 1) * 64, wc0 = (wave & 1) * 64;
  const int srow = tid >> 2;
  const int sk   = ((tid & 3) ^ ((tid >> 3) & 3)) * 8;
  const int wu   = (tid & ~63) * 8;

  f32x4 acc[4][4];
#pragma unroll
  for (int mi = 0; mi < 4; ++mi)
#pragma unroll
    for (int ni = 0; ni < 4; ++ni) acc[mi][ni] = (f32x4){0.f, 0.f, 0.f, 0.f};

  auto stage = [&](int buf, int k0) {
    u16* base = lds + buf * 16384;
    gload16(Ahi + (size_t)(row0 + srow) * lda + k0 + sk,      base + wu);
    gload16(Ahi + (size_t)(row0 + 64 + srow) * lda + k0 + sk, base + 2048 + wu);
    gload16(Alo + (size_t)(row0 + srow) * lda + k0 + sk,      base + 4096 + wu);
    gload16(Alo + (size_t)(row0 + 64 + srow) * lda + k0 + sk, base + 6144 + wu);
    gload16(Bthi + (size_t)(col0 + srow) * ldb + k0 + sk,      base + 8192 + wu);
    gload16(Bthi + (size_t)(col0 + 64 + srow) * ldb + k0 + sk, base + 10240 + wu);
    gload16(Btlo + (size_t)(col0 + srow) * ldb + k0 + sk,      base + 12288 + wu);
    gload16(Btlo + (size_t)(col0 + 64 + srow) * ldb + k0 + sk, base + 14336 + wu);
  };
  auto compute = [&](int buf) {
    u16* base = lds + buf * 16384;
    const int ko_swz = ((lane >> 4) ^ ((lane >> 1) & 3)) * 8;
    const int ar = lane & 15;
    bf16x8 ah[4], al[4], bh[4], bl[4];
#pragma unroll
    for (int mi = 0; mi < 4; ++mi) {
      const int r = wr0 + mi * 16 + ar;
      ah[mi] = *(const bf16x8*)&base[r * 32 + ko_swz];
      al[mi] = *(const bf16x8*)&base[4096 + r * 32 + ko_swz];
    }
#pragma unroll
    for (int ni = 0; ni < 4; ++ni) {
      const int c = wc0 + ni * 16 + ar;
      bh[ni] = *(const bf16x8*)&base[8192 + c * 32 + ko_swz];
      bl[ni] = *(const bf16x8*)&base[12288 + c * 32 + ko_swz];
    }
#pragma unroll
    for (int mi = 0; mi < 4; ++mi)
#pragma unroll
      for (int ni = 0; ni < 4; ++ni) {
        acc[mi][ni] = __builtin_amdgcn_mfma_f32_16x16x32_bf16(ah[mi], bh[ni], acc[mi][ni], 0, 0, 0);
        acc[mi][ni] = __builtin_amdgcn_mfma_f32_16x16x32_bf16(ah[mi], bl[ni], acc[mi][ni], 0, 0, 0);
        acc[mi][ni] = __builtin_amdgcn_mfma_f32_16x16x32_bf16(al[mi], bh[ni], acc[mi][ni], 0, 0, 0);
      }
  };

  const int nk = K >> 5;
  stage(0, 0);
  int cur = 0;
  for (int k = 0; k < nk; ++k) {
    if (k + 1 < nk) {
      stage(cur ^ 1, (k + 1) * 32);
      asm volatile("s_waitcnt vmcnt(8)" ::: "memory");
    } else {
      asm volatile("s_waitcnt vmcnt(0)" ::: "memory");
    }
    __builtin_amdgcn_s_barrier();
    compute(cur);
    __builtin_amdgcn_s_barrier();
    cur ^= 1;
  }

#pragma unroll
  for (int mi = 0; mi < 4; ++mi)
#pragma unroll
    for (int ni = 0; ni < 4; ++ni) {
      const int gcol = col0 + wc0 + ni * 16 + (lane & 15);
      const float b = HASBIAS ? bias[gcol] : 0.f;
#pragma unroll
      for (int r = 0; r < 4; ++r) {
        const int grow = row0 + wr0 + mi * 16 + (lane >> 4) * 4 + r;
        Cf[(size_t)grow * N + gcol] = acc[mi][ni][r] + b;
      }
    }
}

// GEMM1: 512 linear blocks, XCD-banded (r14-proven).
__global__ __launch_bounds__(256, 2) void gemm1_kernel(
    const u16* __restrict__ a_hi, const u16* __restrict__ a_lo,
    const u16* __restrict__ w1t_hi, const u16* __restrict__ w1t_lo,
    const float* __restrict__ b1,
    u16* __restrict__ h_hi, u16* __restrict__ h_lo) {
  __shared__ u16 lds[3 * 12288];
  const int r = blockIdx.x;              // 0..511
  const int x = r & 7;                   // XCD (dispatch round-robin)
  const int i = r >> 3;                  // 0..63 within XCD
  const int by = x * 4 + (i >> 4);       // 4 row-bands per XCD
  const int bx = i & 15;
  gemm_pipe3<true, true, true>(bx, by,
      a_hi, a_lo, K1PAD, w1t_hi, w1t_lo, K1PAD, b1,
      nullptr, h_hi, h_lo, HMLP, K1PAD, lds);
}

// Fused: Z1 (128 a1p blocks, same-band-same-XCD) + adj (1024, 2-D XCD tiles)
__global__ __launch_bounds__(256, 2) void fused2_kernel(
    const u16* __restrict__ h_hi, const u16* __restrict__ h_lo,
    const u16* __restrict__ w2t_hi, const u16* __restrict__ w2t_lo,
    const float* __restrict__ b2, float* __restrict__ adj,
    const float* __restrict__ node,
    const u16* __restrict__ w1ct_hi, const u16* __restrict__ w1ct_lo,
    float* __restrict__ Z1) {
  __shared__ u16 lds[3 * 12288];          // 72 KB (a1p); pipe128 uses 64 KB
  const int bid = blockIdx.x;
  if (bid < 128) {          // Z1 = node @ conv_w1 (fp32 out, no bias)
    const int x = bid & 7;                // XCD
    const int i = bid >> 3;               // 0..15 within XCD
    const int by = x * 4 + (i >> 2);      // 4 bands per XCD (r15-proven)
    const int bx = i & 3;
    gemm_a1p(bx, by,
             node, D_DIM, w1ct_hi, w1ct_lo, D_DIM,
             Z1, 256, D_DIM, lds);
  } else {                  // adj = h @ W2 + b2; 2-D XCD partition (8by x 16bx)
    const int r = bid - 128;              // 1024 blocks; (r+128)%8 == r%8
    const int x = r & 7;                  // XCD
    const int i = r >> 3;                 // 0..127 within XCD
    const int rg = x >> 1, cg = x & 1;    // 4 row-groups x 2 col-groups
    const int by = rg * 8 + (i >> 4);     // 8 by-rows per region
    const int bx = cg * 16 + (i & 15);    // 16 bx-cols per region
    gemm_pipe128<true>(bx, by,
        h_hi, h_lo, HMLP, w2t_hi, w2t_lo, HMLP, b2,
        adj, N_NODES, HMLP, lds);
  }
}

// ---------------------------------------------------------------------------
// Small fp32 GEMM (Z2 only): 64x64 tile, BK=16, 256 threads, 4x4/thread.
// ---------------------------------------------------------------------------
__global__ __launch_bounds__(256) void gemm_small(
    const float* __restrict__ A, const float* __restrict__ B,
    float* __restrict__ C, int M, int Ncols, int K) {
  __shared__ float As[16][68];
  __shared__ float Bs[16][68];
  const int tid = threadIdx.x;
  const int row0 = blockIdx.y * 64, col0 = blockIdx.x * 64;
  const int tx = tid & 15, ty = tid >> 4;
  const int arow = tid >> 2, acol = (tid & 3) * 4;
  const int brow = tid >> 4, bcol = (tid & 15) * 4;

  float acc[4][4];
#pragma unroll
  for (int i = 0; i < 4; ++i)
#pragma unroll
    for (int j = 0; j < 4; ++j) acc[i][j] = 0.f;

  for (int k0 = 0; k0 < K; k0 += 16) {
    const float4 a4 = *(const float4*)(A + (size_t)(row0 + arow) * K + k0 + acol);
    const float4 b4 = *(const float4*)(B + (size_t)(k0 + brow) * Ncols + col0 + bcol);
    __syncthreads();
    As[acol + 0][arow] = a4.x; As[acol + 1][arow] = a4.y;
    As[acol + 2][arow] = a4.z; As[acol + 3][arow] = a4.w;
    *(float4*)&Bs[brow][bcol] = b4;
    __syncthreads();
#pragma unroll
    for (int k = 0; k < 16; ++k) {
      float av[4], bw[4];
      *(float4*)&av[0] = *(const float4*)&As[k][ty * 4];
      *(float4*)&bw[0] = *(const float4*)&Bs[k][tx * 4];
#pragma unroll
      for (int i = 0; i < 4; ++i)
#pragma unroll
        for (int j = 0; j < 4; ++j) acc[i][j] += av[i] * bw[j];
    }
  }

#pragma unroll
  for (int i = 0; i < 4; ++i) {
    const int r = row0 + ty * 4 + i;
    float4 v;
    v.x = acc[i][0]; v.y = acc[i][1]; v.z = acc[i][2]; v.w = acc[i][3];
    *(float4*)(C + (size_t)r * Ncols + col0 + tx * 4) = v;
  }
}

// ---------------------------------------------------------------------------
// Top-K: one block/row; per-thread cached argmax + shfl_xor butterfly;
// only the winner thread rescans its 16 elements. Tie -> lowest index.
// ---------------------------------------------------------------------------
__global__ __launch_bounds__(256) void topk_kernel(
    const float* __restrict__ adj, float* __restrict__ vals,
    int* __restrict__ idxo, float* __restrict__ dinv) {
  __shared__ float sv[N_NODES];
  __shared__ float rw[4];
  __shared__ int   iw[4];
  const int n = blockIdx.x, tid = threadIdx.x;
  const int lane = tid & 63, wave = tid >> 6;
  const float4* rowp = (const float4*)(adj + (size_t)n * N_NODES);

  float mv = -FLT_MAX; int mi = 0x7FFFFFFF;
  for (int g = tid; g < N_NODES / 4; g += 256) {
    const float4 v4 = rowp[g];
    *(float4*)&sv[g * 4] = v4;
    if (v4.x > mv) { mv = v4.x; mi = g * 4 + 0; }
    if (v4.y > mv) { mv = v4.y; mi = g * 4 + 1; }
    if (v4.z > mv) { mv = v4.z; mi = g * 4 + 2; }
    if (v4.w > mv) { mv = v4.w; mi = g * 4 + 3; }
  }

  float sum = 0.f;
  for (int it = 0; it < TOPK; ++it) {
    float bv = mv; int bi = mi;
#pragma unroll
    for (int off = 1; off < 64; off <<= 1) {
      const float ov = __shfl_xor(bv, off);
      const int   oi = __shfl_xor(bi, off);
      if (ov > bv || (ov == bv && oi < bi)) { bv = ov; bi = oi; }
    }
    if (lane == 0) { rw[wave] = bv; iw[wave] = bi; }
    __syncthreads();
    bv = rw[0]; bi = iw[0];
#pragma unroll
    for (int w = 1; w < 4; ++w) {
      const float ov = rw[w]; const int oi = iw[w];
      if (ov > bv || (ov == bv && oi < bi)) { bv = ov; bi = oi; }
    }
    if (tid == 0) {
      vals[(size_t)n * TOPK + it] = bv;
      idxo[(size_t)n * TOPK + it] = bi;
    }
    sum += bv;
    if (tid == ((bi >> 2) & 255)) {        // owner removes + rescans its 16
      sv[bi] = -FLT_MAX;
      mv = -FLT_MAX; mi = 0x7FFFFFFF;
      for (int g = tid; g < N_NODES / 4; g += 256) {
#pragma unroll
        for (int e = 0; e < 4; ++e) {
          const float v = sv[g * 4 + e];
          if (v > mv) { mv = v; mi = g * 4 + e; }
        }
      }
    }
    __syncthreads();
  }
  if (tid == 0)
    dinv[n] = (sum > 0.f) ? rsqrtf(fmaxf(sum, 1e-12f)) : 0.f;
}

// out[n,f] = bias[f] + sum_k vals[n,k]*dinv[n]*dinv[idx]*Z[idx[n,k], f]
__global__ __launch_bounds__(256) void agg_kernel(
    const float* __restrict__ Z, const float* __restrict__ vals,
    const int* __restrict__ idxo, const float* __restrict__ dinv,
    const float* __restrict__ bias, float* __restrict__ out) {
  const int n = blockIdx.x, f = threadIdx.x;
  const float dn = dinv[n];
  float acc = bias[f];
#pragma unroll
  for (int k = 0; k < TOPK; ++k) {
    const int   j = idxo[n * TOPK + k];
    const float w = vals[n * TOPK + k] * dn * dinv[j];
    acc += w * Z[(size_t)j * 256 + f];
  }
  out[(size_t)n * 256 + f] = acc;
}

// BatchNorm stats: 128 partial slabs of 32 rows, then tree reduce.
__global__ __launch_bounds__(256) void bn_partial(
    const float* __restrict__ x, float* __restrict__ partial) {
  const int b = blockIdx.x, c = threadIdx.x;
  float s = 0.f, s2 = 0.f;
  for (int r = b * 32; r < b * 32 + 32; ++r) {
    const float v = x[(size_t)r * 256 + c];
    s += v; s2 += v * v;
  }
  partial[(size_t)b * 512 + c]       = s;
  partial[(size_t)b * 512 + 256 + c] = s2;
}

__global__ __launch_bounds__(256) void bn_reduce(
    const float* __restrict__ partial, float* __restrict__ colstats) {
  const int j = blockIdx.x, t = threadIdx.x;
  __shared__ float red[128];
  if (t < 128) red[t] = partial[(size_t)t * 512 + j];
  __syncthreads();
  for (int s = 64; s > 0; s >>= 1) {
    if (t < s) red[t] += red[t + s];
    __syncthreads();
  }
  if (t == 0) colstats[j] = red[0];
}

__global__ __launch_bounds__(256) void bn_apply(
    float* __restrict__ x, const float* __restrict__ colstats,
    const float* __restrict__ gamma, const float* __restrict__ beta) {
  const int i = blockIdx.x * 256 + threadIdx.x;
  const int c = i & 255;
  const float mean = colstats[c] * (1.f / 4096.f);
  float var = colstats[256 + c] * (1.f / 4096.f) - mean * mean;
  var = fmaxf(var, 0.f);
  const float v = (x[i] - mean) * rsqrtf(var + 1e-5f) * gamma[c] + beta[c];
  x[i] = fmaxf(v, 0.f);
}

// ---------------------------------------------------------------------------
extern "C" void kernel_launch(void* const* d_in, const int* in_sizes, int n_in,
                              void* d_out, int out_size, void* d_ws, size_t ws_size,
                              hipStream_t stream) {
  const float* probs   = (const float*)d_in[0];
  const float* bbox    = (const float*)d_in[1];
  const float* query   = (const float*)d_in[2];
  const float* node    = (const float*)d_in[3];
  const float* mlp_w1  = (const float*)d_in[4];
  const float* mlp_b1  = (const float*)d_in[5];
  const float* mlp_w2  = (const float*)d_in[6];
  const float* mlp_b2  = (const float*)d_in[7];
  const float* conv_w1 = (const float*)d_in[8];
  const float* conv_b1 = (const float*)d_in[9];
  const float* conv_w2 = (const float*)d_in[10];
  const float* conv_b2 = (const float*)d_in[11];
  const float* gamma   = (const float*)d_in[12];
  const float* beta    = (const float*)d_in[13];

  // --- workspace layout (peak 30,408,704 floats = 121.6 MB; r2 proved 123.2) ---
  float* ws = (float*)d_ws;
  size_t off = 0;
  // R1: a planes [4096][5120] u16 x2 during gemm1; adj + spare afterwards
  float* R1 = ws + off;  off += (size_t)N_NODES * K1PAD;         // 20,971,520 f
  u16* a_hi = (u16*)R1;
  u16* a_lo = a_hi + (size_t)N_NODES * K1PAD;
  float* adj = R1;                                               // 16,777,216 f
  float* spare = R1 + (size_t)N_NODES * N_NODES;                 //  4,194,304 f
  float* Z1   = spare;
  float* vals = spare + (size_t)N_NODES * 256;
  int*   idxo = (int*)(vals + (size_t)N_NODES * TOPK);
  float* dinv = (float*)idxo + (size_t)N_NODES * TOPK;
  float* partial  = dinv + N_NODES;
  float* colstats = partial + 128 * 512;
  // R2: w1t during gemm1; w2t + w1ct afterwards; out1 overlays w1ct
  float* R2 = ws + off;  off += (size_t)HMLP * K1PAD;            //  5,242,880 f
  u16* w1t_hi = (u16*)R2;
  u16* w1t_lo = w1t_hi + (size_t)HMLP * K1PAD;
  u16* w2t_hi = (u16*)R2;
  u16* w2t_lo = w2t_hi + (size_t)N_NODES * HMLP;
  u16* w1ct_hi = (u16*)(R2 + (size_t)N_NODES * HMLP);
  u16* w1ct_lo = w1ct_hi + (size_t)256 * D_DIM;
  float* out1 = R2 + (size_t)N_NODES * HMLP;                     // post-fused2
  // R3: h planes
  float* R3 = ws + off;  off += (size_t)N_NODES * HMLP;          //  4,194,304 f
  u16* h_hi = (u16*)R3;
  u16* h_lo = h_hi + (size_t)N_NODES * HMLP;
  float* Z2 = adj;                       // adj dead after topk

  // 1) a planes = split([query | probs | bbox | 0])     [4096][5120]
  a_split<<<(N_NODES * K1PAD) / (256 * 8), 256, 0, stream>>>(
      query, probs, bbox, a_hi, a_lo);
  // 2) W1t hi/lo = split-transpose(mlp_w1)              [1024][5120]
  transpose_split<<<dim3(K1PAD / 64, HMLP / 64), 256, 0, stream>>>(
      mlp_w1, KCAT, HMLP, K1PAD, w1t_hi, w1t_lo);
  // 3) h = relu(Apad @ W1 + b1) -> bf16 hi/lo           (4096 x 1024)
  gemm1_kernel<<<512, 256, 0, stream>>>(
      a_hi, a_lo, w1t_hi, w1t_lo, mlp_b1, h_hi, h_lo);
  // 4) W2t hi/lo = split-transpose(mlp_w2)              [4096][1024]
  transpose_split<<<dim3(HMLP / 64, N_NODES / 64), 256, 0, stream>>>(
      mlp_w2, HMLP, N_NODES, HMLP, w2t_hi, w2t_lo);
  // 5) W1Ct hi/lo = split-transpose(conv_w1)            [256][4096]
  transpose_split<<<dim3(D_DIM / 64, 256 / 64), 256, 0, stream>>>(
      conv_w1, D_DIM, 256, D_DIM, w1ct_hi, w1ct_lo);
  // 6) fused: Z1 (128 blocks, band-local) + adj (1024, 2-D XCD tiles)
  fused2_kernel<<<128 + (N_NODES / 128) * (N_NODES / 128), 256, 0, stream>>>(
      h_hi, h_lo, w2t_hi, w2t_lo, mlp_b2, adj, node, w1ct_hi, w1ct_lo, Z1);
  // 7) top-32 per row + dinv
  topk_kernel<<<N_NODES, 256, 0, stream>>>(adj, vals, idxo, dinv);
  // 8) out1 = gather-agg(Z1) + conv_b1
  agg_kernel<<<N_NODES, 256, 0, stream>>>(Z1, vals, idxo, dinv, conv_b1, out1);
  // 9) BatchNorm (batch stats) + relu, in place
  bn_partial<<<128, 256, 0, stream>>>(out1, partial);
  bn_reduce<<<512, 256, 0, stream>>>(partial, colstats);
  bn_apply<<<N_NODES, 256, 0, stream>>>(out1, colstats, gamma, beta);
  // 10) Z2 = y @ conv_w2 (fp32)                         (4096 x 256)
  gemm_small<<<dim3(256 / 64, N_NODES / 64), 256, 0, stream>>>(
      out1, conv_w2, Z2, N_NODES, 256, 256);
  // 11) out = gather-agg(Z2) + conv_b2
  agg_kernel<<<N_NODES, 256, 0, stream>>>(Z2, vals, idxo, dinv, conv_b2, (float*)d_out);
}

// Round 18
// 521.516 us; speedup vs baseline: 1.0561x; 1.0290x over previous
//
#include <hip/hip_runtime.h>
#include <cfloat>

#define N_NODES 4096
#define C1_DIM  1001
#define D_DIM   4096
#define HMLP    1024
#define KCAT    (D_DIM + C1_DIM + 4)   // 5101
#define K1PAD   5120                   // padded, multiple of 32
#define TOPK    32

typedef unsigned short u16;
typedef __bf16 bf16x8 __attribute__((ext_vector_type(8)));
typedef float  f32x4  __attribute__((ext_vector_type(4)));

// RNE round-to-bf16 (round-4-proven numerics).
__device__ __forceinline__ unsigned rne_bits(float x) {
  const unsigned u = __float_as_uint(x);
  return u + 0x7FFFu + ((u >> 16) & 1u);
}

__device__ __forceinline__ void gload16(const void* g, void* l) {
  __builtin_amdgcn_global_load_lds(
      (const __attribute__((address_space(1))) unsigned int*)g,
      (__attribute__((address_space(3))) unsigned int*)l, 16, 0, 0);
}

// ---------------------------------------------------------------------------
// transpose body: out_hi/lo[C][Rpad] = split-bf16 transpose of in[R][C]
// ---------------------------------------------------------------------------
__device__ __forceinline__ void transpose_body(
    const float* __restrict__ in, int R, int C, int Rpad,
    u16* __restrict__ out_hi, u16* __restrict__ out_lo,
    int bxi, int byi, float (*t)[65]) {
  const int rb = bxi * 64;
  const int cb = byi * 64;
  const int tid = threadIdx.x;
  const int lr = tid >> 6, lc = tid & 63;
#pragma unroll
  for (int i = 0; i < 16; ++i) {
    const int r = lr + i * 4;
    const int gr = rb + r;
    t[r][lc] = (gr < R) ? in[(size_t)gr * C + cb + lc] : 0.f;
  }
  __syncthreads();
#pragma unroll
  for (int i = 0; i < 16; ++i) {
    const int c = lr + i * 4;
    const float v = t[lc][c];
    const unsigned vh = rne_bits(v);
    const float r = v - __uint_as_float(vh & 0xFFFF0000u);
    const size_t o = (size_t)(cb + c) * Rpad + rb + lc;
    out_hi[o] = (u16)(vh >> 16);
    out_lo[o] = (u16)(rne_bits(r) >> 16);
  }
}

// a_split body: 8 cols of the padded [4096][5120] a-planes per thread.
__device__ __forceinline__ void a_split_body(
    const float* __restrict__ query, const float* __restrict__ probs,
    const float* __restrict__ bbox,
    u16* __restrict__ hi, u16* __restrict__ lo, int blk) {
  const size_t idx = ((size_t)blk * 256 + threadIdx.x) * 8;
  const int row = (int)(idx / K1PAD);
  const int col = (int)(idx - (size_t)row * K1PAD);
  float xs[8];
  if (col < D_DIM) {
    const float4 x0 = *(const float4*)(query + (size_t)row * D_DIM + col);
    const float4 x1 = *(const float4*)(query + (size_t)row * D_DIM + col + 4);
    xs[0]=x0.x; xs[1]=x0.y; xs[2]=x0.z; xs[3]=x0.w;
    xs[4]=x1.x; xs[5]=x1.y; xs[6]=x1.z; xs[7]=x1.w;
  } else {
#pragma unroll
    for (int e = 0; e < 8; ++e) {
      const int c = col + e - D_DIM;
      xs[e] = (c < C1_DIM) ? probs[(size_t)row * C1_DIM + c]
            : (c < C1_DIM + 4) ? bbox[(size_t)row * 4 + (c - C1_DIM)] : 0.f;
    }
  }
  unsigned hw[4], lw[4];
#pragma unroll
  for (int p = 0; p < 4; ++p) {
    const unsigned v0 = rne_bits(xs[2*p]);
    const unsigned v1 = rne_bits(xs[2*p+1]);
    hw[p] = (v1 & 0xFFFF0000u) | (v0 >> 16);
    const float r0 = xs[2*p]   - __uint_as_float(v0 & 0xFFFF0000u);
    const float r1 = xs[2*p+1] - __uint_as_float(v1 & 0xFFFF0000u);
    lw[p] = (rne_bits(r1) & 0xFFFF0000u) | (rne_bits(r0) >> 16);
  }
  *(uint4*)(hi + idx) = make_uint4(hw[0], hw[1], hw[2], hw[3]);
  *(uint4*)(lo + idx) = make_uint4(lw[0], lw[1], lw[2], lw[3]);
}

// prep1: a_split (10240 blocks) + w1t split-transpose (1280 blocks)
__global__ __launch_bounds__(256) void prep1_kernel(
    const float* __restrict__ query, const float* __restrict__ probs,
    const float* __restrict__ bbox, const float* __restrict__ mlp_w1,
    u16* __restrict__ a_hi, u16* __restrict__ a_lo,
    u16* __restrict__ w1t_hi, u16* __restrict__ w1t_lo) {
  __shared__ float t[64][65];
  const int b = blockIdx.x;
  if (b < 10240) {
    a_split_body(query, probs, bbox, a_hi, a_lo, b);
  } else {
    const int bb = b - 10240;              // 0..1279; grid was (80, 16)
    transpose_body(mlp_w1, KCAT, HMLP, K1PAD, w1t_hi, w1t_lo,
                   bb % 80, bb / 80, t);
  }
}

// prep2 (after gemm1): w2t (1024 blocks) + w1ct (256 blocks)
__global__ __launch_bounds__(256) void prep2_kernel(
    const float* __restrict__ mlp_w2, const float* __restrict__ conv_w1,
    u16* __restrict__ w2t_hi, u16* __restrict__ w2t_lo,
    u16* __restrict__ w1ct_hi, u16* __restrict__ w1ct_lo) {
  __shared__ float t[64][65];
  const int b = blockIdx.x;
  if (b < 1024) {                          // grid was (16, 64)
    transpose_body(mlp_w2, HMLP, N_NODES, HMLP, w2t_hi, w2t_lo,
                   b & 15, b >> 4, t);
  } else {                                 // grid was (64, 4)
    const int bb = b - 1024;
    transpose_body(conv_w1, D_DIM, 256, D_DIM, w1ct_hi, w1ct_lo,
                   bb & 63, bb >> 6, t);
  }
}

// ===========================================================================
// u16-plane swizzle (r9-proven, 0 conflicts): stored 16B-chunk =
// logical ^ ((row>>1)&3); gload SOURCE pre-swizzled (sk), LDS dest linear;
// reads use ko_swz. fp32-A swizzle (Z1): stored = logical ^ (row&7).
// ===========================================================================

template<bool RELU, bool OUT_SPLIT, bool HASBIAS>
__device__ __forceinline__ void epilogue_64(
    f32x4 (&acc)[4][2], int row0, int col0, int wr0, int wc0, int lane,
    const float* bias, float* Cf, u16* Chi, u16* Clo, int N) {
#pragma unroll
  for (int mi = 0; mi < 4; ++mi)
#pragma unroll
    for (int ni = 0; ni < 2; ++ni) {
      const int gcol = col0 + wc0 + ni * 16 + (lane & 15);
      const float b = HASBIAS ? bias[gcol] : 0.f;
#pragma unroll
      for (int r = 0; r < 4; ++r) {
        const int grow = row0 + wr0 + mi * 16 + (lane >> 4) * 4 + r;
        float v = acc[mi][ni][r] + b;
        if (RELU) v = fmaxf(v, 0.f);
        if (OUT_SPLIT) {
          const unsigned vh = rne_bits(v);
          Chi[(size_t)grow * N + gcol] = (u16)(vh >> 16);
          const float rr = v - __uint_as_float(vh & 0xFFFF0000u);
          Clo[(size_t)grow * N + gcol] = (u16)(rne_bits(rr) >> 16);
        } else {
          Cf[(size_t)grow * N + gcol] = v;
        }
      }
    }
}

// ---------------------------------------------------------------------------
// gemm_pipe3 (r10-proven): BM=128/BN=64/BK=32, 3 LDS buffers, counted vmcnt.
// ---------------------------------------------------------------------------
template<bool RELU, bool OUT_SPLIT, bool HASBIAS>
__device__ __forceinline__ void gemm_pipe3(
    int bx, int by,
    const u16* __restrict__ Ahi, const u16* __restrict__ Alo, int lda,
    const u16* __restrict__ Bthi, const u16* __restrict__ Btlo, int ldb,
    const float* __restrict__ bias,
    float* __restrict__ Cf, u16* __restrict__ Chi, u16* __restrict__ Clo,
    int N, int K, u16* lds) {
  const int tid = threadIdx.x;
  const int lane = tid & 63, wave = tid >> 6;
  const int row0 = by * 128, col0 = bx * 64;
  const int wr0 = (wave >> 1) * 64, wc0 = (wave & 1) * 32;
  const int srow = tid >> 2;
  const int sk   = ((tid & 3) ^ ((tid >> 3) & 3)) * 8;
  const int wu   = (tid & ~63) * 8;

  f32x4 acc[4][2];
#pragma unroll
  for (int mi = 0; mi < 4; ++mi)
#pragma unroll
    for (int ni = 0; ni < 2; ++ni) acc[mi][ni] = (f32x4){0.f, 0.f, 0.f, 0.f};

  auto stage = [&](int buf, int k0) {
    u16* base = lds + buf * 12288;
    gload16(Ahi + (size_t)(row0 + srow) * lda + k0 + sk,      base + wu);
    gload16(Ahi + (size_t)(row0 + 64 + srow) * lda + k0 + sk, base + 2048 + wu);
    gload16(Alo + (size_t)(row0 + srow) * lda + k0 + sk,      base + 4096 + wu);
    gload16(Alo + (size_t)(row0 + 64 + srow) * lda + k0 + sk, base + 6144 + wu);
    gload16(Bthi + (size_t)(col0 + srow) * ldb + k0 + sk, base + 8192 + wu);
    gload16(Btlo + (size_t)(col0 + srow) * ldb + k0 + sk, base + 10240 + wu);
  };
  auto compute = [&](int buf) {
    u16* base = lds + buf * 12288;
    const int ko_swz = ((lane >> 4) ^ ((lane >> 1) & 3)) * 8;
    const int ar = lane & 15;
    bf16x8 ah[4], al[4], bh[2], bl[2];
#pragma unroll
    for (int mi = 0; mi < 4; ++mi) {
      const int r = wr0 + mi * 16 + ar;
      ah[mi] = *(const bf16x8*)&base[r * 32 + ko_swz];
      al[mi] = *(const bf16x8*)&base[4096 + r * 32 + ko_swz];
    }
#pragma unroll
    for (int ni = 0; ni < 2; ++ni) {
      const int c = wc0 + ni * 16 + ar;
      bh[ni] = *(const bf16x8*)&base[8192 + c * 32 + ko_swz];
      bl[ni] = *(const bf16x8*)&base[10240 + c * 32 + ko_swz];
    }
#pragma unroll
    for (int mi = 0; mi < 4; ++mi)
#pragma unroll
      for (int ni = 0; ni < 2; ++ni) {
        acc[mi][ni] = __builtin_amdgcn_mfma_f32_16x16x32_bf16(ah[mi], bh[ni], acc[mi][ni], 0, 0, 0);
        acc[mi][ni] = __builtin_amdgcn_mfma_f32_16x16x32_bf16(ah[mi], bl[ni], acc[mi][ni], 0, 0, 0);
        acc[mi][ni] = __builtin_amdgcn_mfma_f32_16x16x32_bf16(al[mi], bh[ni], acc[mi][ni], 0, 0, 0);
      }
  };

  const int nk = K >> 5;
  stage(0, 0);
  stage(1, 32);
  int cb = 0;
  for (int k = 0; k < nk; ++k) {
    if (k + 2 < nk) {
      int sb = cb + 2; if (sb >= 3) sb -= 3;
      stage(sb, (k + 2) * 32);
      asm volatile("s_waitcnt vmcnt(12)" ::: "memory");
    } else if (k + 1 < nk) {
      asm volatile("s_waitcnt vmcnt(6)" ::: "memory");
    } else {
      asm volatile("s_waitcnt vmcnt(0)" ::: "memory");
    }
    __builtin_amdgcn_s_barrier();
    compute(cb);
    __builtin_amdgcn_s_barrier();
    ++cb; if (cb >= 3) cb -= 3;
  }

  epilogue_64<RELU, OUT_SPLIT, HASBIAS>(acc, row0, col0, wr0, wc0, lane,
                                        bias, Cf, Chi, Clo, N);
}

// ---------------------------------------------------------------------------
// gemm_a1p (r13-proven, Z1): fp32 A staged raw via gload16, register split,
// 3-buffer counted vmcnt.
// ---------------------------------------------------------------------------
__device__ __forceinline__ void gemm_a1p(
    int bx, int by,
    const float* __restrict__ Aq, int lda,
    const u16* __restrict__ Bthi, const u16* __restrict__ Btlo, int ldb,
    float* __restrict__ Cf, int N, int K, u16* lds) {
  const int tid = threadIdx.x;
  const int lane = tid & 63, wave = tid >> 6;
  const int row0 = by * 128, col0 = bx * 64;
  const int wr0 = (wave >> 1) * 64, wc0 = (wave & 1) * 32;
  const int srow = tid >> 2;
  const int sk   = ((tid & 3) ^ ((tid >> 3) & 3)) * 8;
  const int wu   = (tid & ~63) * 8;
  const int arowA = tid >> 3;
  const int skA   = ((tid & 7) ^ ((tid >> 3) & 7)) * 4;  // fp32 units

  f32x4 acc[4][2];
#pragma unroll
  for (int mi = 0; mi < 4; ++mi)
#pragma unroll
    for (int ni = 0; ni < 2; ++ni) acc[mi][ni] = (f32x4){0.f, 0.f, 0.f, 0.f};

  auto stage = [&](int buf, int k0) {
    u16* base = lds + buf * 12288;
#pragma unroll
    for (int j = 0; j < 4; ++j) {
      gload16(Aq + (size_t)(row0 + 32 * j + arowA) * lda + k0 + skA,
              base + j * 2048 + wu);
    }
    gload16(Bthi + (size_t)(col0 + srow) * ldb + k0 + sk, base + 8192 + wu);
    gload16(Btlo + (size_t)(col0 + srow) * ldb + k0 + sk, base + 10240 + wu);
  };
  auto compute = [&](int buf) {
    u16* base = lds + buf * 12288;
    const float* Af = (const float*)base;
    const int ko_swz = ((lane >> 4) ^ ((lane >> 1) & 3)) * 8;
    const int c = lane >> 4;
    const int ar = lane & 15;
    bf16x8 ah[4], al[4], bh[2], bl[2];
#pragma unroll
    for (int mi = 0; mi < 4; ++mi) {
      const int r = wr0 + mi * 16 + ar;
      const int s = ar & 7;
      const f32x4 a0 = *(const f32x4*)&Af[r * 32 + (((2 * c) ^ s) * 4)];
      const f32x4 a1 = *(const f32x4*)&Af[r * 32 + (((2 * c + 1) ^ s) * 4)];
      const float xs[8] = {a0[0], a0[1], a0[2], a0[3], a1[0], a1[1], a1[2], a1[3]};
      union { u16 u[8]; bf16x8 v; } H, L;
#pragma unroll
      for (int e = 0; e < 8; ++e) {
        const unsigned vh = rne_bits(xs[e]);
        H.u[e] = (u16)(vh >> 16);
        const float rr = xs[e] - __uint_as_float(vh & 0xFFFF0000u);
        L.u[e] = (u16)(rne_bits(rr) >> 16);
      }
      ah[mi] = H.v; al[mi] = L.v;
    }
#pragma unroll
    for (int ni = 0; ni < 2; ++ni) {
      const int cc = wc0 + ni * 16 + ar;
      bh[ni] = *(const bf16x8*)&base[8192 + cc * 32 + ko_swz];
      bl[ni] = *(const bf16x8*)&base[10240 + cc * 32 + ko_swz];
    }
#pragma unroll
    for (int mi = 0; mi < 4; ++mi)
#pragma unroll
      for (int ni = 0; ni < 2; ++ni) {
        acc[mi][ni] = __builtin_amdgcn_mfma_f32_16x16x32_bf16(ah[mi], bh[ni], acc[mi][ni], 0, 0, 0);
        acc[mi][ni] = __builtin_amdgcn_mfma_f32_16x16x32_bf16(ah[mi], bl[ni], acc[mi][ni], 0, 0, 0);
        acc[mi][ni] = __builtin_amdgcn_mfma_f32_16x16x32_bf16(al[mi], bh[ni], acc[mi][ni], 0, 0, 0);
      }
  };

  const int nk = K >> 5;
  stage(0, 0);
  stage(1, 32);
  int cb = 0;
  for (int k = 0; k < nk; ++k) {
    if (k + 2 < nk) {
      int sb = cb + 2; if (sb >= 3) sb -= 3;
      stage(sb, (k + 2) * 32);
      asm volatile("s_waitcnt vmcnt(12)" ::: "memory");
    } else if (k + 1 < nk) {
      asm volatile("s_waitcnt vmcnt(6)" ::: "memory");
    } else {
      asm volatile("s_waitcnt vmcnt(0)" ::: "memory");
    }
    __builtin_amdgcn_s_barrier();
    compute(cb);
    __builtin_amdgcn_s_barrier();
    ++cb; if (cb >= 3) cb -= 3;
  }

  epilogue_64<false, false, false>(acc, row0, col0, wr0, wc0, lane,
                                   nullptr, Cf, nullptr, nullptr, N);
}

// ---------------------------------------------------------------------------
// gemm_pipe128 (r12-proven): BM=128/BN=128/BK=32, 2 LDS buffers, counted
// vmcnt(8). Wave tile 64x64.
// ---------------------------------------------------------------------------
template<bool HASBIAS>
__device__ __forceinline__ void gemm_pipe128(
    int bx, int by,
    const u16* __restrict__ Ahi, const u16* __restrict__ Alo, int lda,
    const u16* __restrict__ Bthi, const u16* __restrict__ Btlo, int ldb,
    const float* __restrict__ bias, float* __restrict__ Cf,
    int N, int K, u16* lds) {
  const int tid = threadIdx.x;
  const int lane = tid & 63, wave = tid >> 6;
  const int row0 = by * 128, col0 = bx * 128;
  const int wr0 = (wave >> 1) * 64, wc0 = (wave & 1) * 64;
  const int srow = tid >> 2;
  const int sk   = ((tid & 3) ^ ((tid >> 3) & 3)) * 8;
  const int wu   = (tid & ~63) * 8;

  f32x4 acc[4][4];
#pragma unroll
  for (int mi = 0; mi < 4; ++mi)
#pragma unroll
    for (int ni = 0; ni < 4; ++ni) acc[mi][ni] = (f32x4){0.f, 0.f, 0.f, 0.f};

  auto stage = [&](int buf, int k0) {
    u16* base = lds + buf * 16384;
    gload16(Ahi + (size_t)(row0 + srow) * lda + k0 + sk,      base + wu);
    gload16(Ahi + (size_t)(row0 + 64 + srow) * lda + k0 + sk, base + 2048 + wu);
    gload16(Alo + (size_t)(row0 + srow) * lda + k0 + sk,      base + 4096 + wu);
    gload16(Alo + (size_t)(row0 + 64 + srow) * lda + k0 + sk, base + 6144 + wu);
    gload16(Bthi + (size_t)(col0 + srow) * ldb + k0 + sk,      base + 8192 + wu);
    gload16(Bthi + (size_t)(col0 + 64 + srow) * ldb + k0 + sk, base + 10240 + wu);
    gload16(Btlo + (size_t)(col0 + srow) * ldb + k0 + sk,      base + 12288 + wu);
    gload16(Btlo + (size_t)(col0 + 64 + srow) * ldb + k0 + sk, base + 14336 + wu);
  };
  auto compute = [&](int buf) {
    u16* base = lds + buf * 16384;
    const int ko_swz = ((lane >> 4) ^ ((lane >> 1) & 3)) * 8;
    const int ar = lane & 15;
    bf16x8 ah[4], al[4], bh[4], bl[4];
#pragma unroll
    for (int mi = 0; mi < 4; ++mi) {
      const int r = wr0 + mi * 16 + ar;
      ah[mi] = *(const bf16x8*)&base[r * 32 + ko_swz];
      al[mi] = *(const bf16x8*)&base[4096 + r * 32 + ko_swz];
    }
#pragma unroll
    for (int ni = 0; ni < 4; ++ni) {
      const int c = wc0 + ni * 16 + ar;
      bh[ni] = *(const bf16x8*)&base[8192 + c * 32 + ko_swz];
      bl[ni] = *(const bf16x8*)&base[12288 + c * 32 + ko_swz];
    }
#pragma unroll
    for (int mi = 0; mi < 4; ++mi)
#pragma unroll
      for (int ni = 0; ni < 4; ++ni) {
        acc[mi][ni] = __builtin_amdgcn_mfma_f32_16x16x32_bf16(ah[mi], bh[ni], acc[mi][ni], 0, 0, 0);
        acc[mi][ni] = __builtin_amdgcn_mfma_f32_16x16x32_bf16(ah[mi], bl[ni], acc[mi][ni], 0, 0, 0);
        acc[mi][ni] = __builtin_amdgcn_mfma_f32_16x16x32_bf16(al[mi], bh[ni], acc[mi][ni], 0, 0, 0);
      }
  };

  const int nk = K >> 5;
  stage(0, 0);
  int cur = 0;
  for (int k = 0; k < nk; ++k) {
    if (k + 1 < nk) {
      stage(cur ^ 1, (k + 1) * 32);
      asm volatile("s_waitcnt vmcnt(8)" ::: "memory");
    } else {
      asm volatile("s_waitcnt vmcnt(0)" ::: "memory");
    }
    __builtin_amdgcn_s_barrier();
    compute(cur);
    __builtin_amdgcn_s_barrier();
    cur ^= 1;
  }

#pragma unroll
  for (int mi = 0; mi < 4; ++mi)
#pragma unroll
    for (int ni = 0; ni < 4; ++ni) {
      const int gcol = col0 + wc0 + ni * 16 + (lane & 15);
      const float b = HASBIAS ? bias[gcol] : 0.f;
#pragma unroll
      for (int r = 0; r < 4; ++r) {
        const int grow = row0 + wr0 + mi * 16 + (lane >> 4) * 4 + r;
        Cf[(size_t)grow * N + gcol] = acc[mi][ni][r] + b;
      }
    }
}

// GEMM1: 512 linear blocks, XCD-banded (r14-proven).
__global__ __launch_bounds__(256, 2) void gemm1_kernel(
    const u16* __restrict__ a_hi, const u16* __restrict__ a_lo,
    const u16* __restrict__ w1t_hi, const u16* __restrict__ w1t_lo,
    const float* __restrict__ b1,
    u16* __restrict__ h_hi, u16* __restrict__ h_lo) {
  __shared__ u16 lds[3 * 12288];
  const int r = blockIdx.x;              // 0..511
  const int x = r & 7;                   // XCD (dispatch round-robin)
  const int i = r >> 3;                  // 0..63 within XCD
  const int by = x * 4 + (i >> 4);       // 4 row-bands per XCD
  const int bx = i & 15;
  gemm_pipe3<true, true, true>(bx, by,
      a_hi, a_lo, K1PAD, w1t_hi, w1t_lo, K1PAD, b1,
      nullptr, h_hi, h_lo, HMLP, K1PAD, lds);
}

// Fused: Z1 (128 a1p blocks, same-band-same-XCD) + adj (1024, 2-D XCD tiles)
__global__ __launch_bounds__(256, 2) void fused2_kernel(
    const u16* __restrict__ h_hi, const u16* __restrict__ h_lo,
    const u16* __restrict__ w2t_hi, const u16* __restrict__ w2t_lo,
    const float* __restrict__ b2, float* __restrict__ adj,
    const float* __restrict__ node,
    const u16* __restrict__ w1ct_hi, const u16* __restrict__ w1ct_lo,
    float* __restrict__ Z1) {
  __shared__ u16 lds[3 * 12288];          // 72 KB (a1p); pipe128 uses 64 KB
  const int bid = blockIdx.x;
  if (bid < 128) {          // Z1 = node @ conv_w1 (fp32 out, no bias)
    const int x = bid & 7;                // XCD
    const int i = bid >> 3;               // 0..15 within XCD
    const int by = x * 4 + (i >> 2);      // 4 bands per XCD (r15-proven)
    const int bx = i & 3;
    gemm_a1p(bx, by,
             node, D_DIM, w1ct_hi, w1ct_lo, D_DIM,
             Z1, 256, D_DIM, lds);
  } else {                  // adj = h @ W2 + b2; 2-D XCD partition (r17-proven)
    const int r = bid - 128;              // 1024 blocks; (r+128)%8 == r%8
    const int x = r & 7;                  // XCD
    const int i = r >> 3;                 // 0..127 within XCD
    const int rg = x >> 1, cg = x & 1;    // 4 row-groups x 2 col-groups
    const int by = rg * 8 + (i >> 4);     // 8 by-rows per region
    const int bx = cg * 16 + (i & 15);    // 16 bx-cols per region
    gemm_pipe128<true>(bx, by,
        h_hi, h_lo, HMLP, w2t_hi, w2t_lo, HMLP, b2,
        adj, N_NODES, HMLP, lds);
  }
}

// ---------------------------------------------------------------------------
// gemm_small_bn (Z2): 64x64 tile, BK=16 fp32; BN-apply + relu fused into the
// A-load (identical op order to the old bn_apply -> bit-identical results).
// A = out1raw [4096][256], stats in colstats[512], B = conv_w2 [256][256].
// ---------------------------------------------------------------------------
__global__ __launch_bounds__(256) void gemm_small_bn(
    const float* __restrict__ A, const float* __restrict__ colstats,
    const float* __restrict__ gamma, const float* __restrict__ beta,
    const float* __restrict__ B, float* __restrict__ C,
    int M, int Ncols, int K) {
  __shared__ float As[16][68];
  __shared__ float Bs[16][68];
  const int tid = threadIdx.x;
  const int row0 = blockIdx.y * 64, col0 = blockIdx.x * 64;
  const int tx = tid & 15, ty = tid >> 4;
  const int arow = tid >> 2, acol = (tid & 3) * 4;
  const int brow = tid >> 4, bcol = (tid & 15) * 4;

  float acc[4][4];
#pragma unroll
  for (int i = 0; i < 4; ++i)
#pragma unroll
    for (int j = 0; j < 4; ++j) acc[i][j] = 0.f;

  for (int k0 = 0; k0 < K; k0 += 16) {
    float4 a4 = *(const float4*)(A + (size_t)(row0 + arow) * K + k0 + acol);
    // fused BN-apply + relu on the 4 loaded channels (c = k0+acol+e)
    float av4[4] = {a4.x, a4.y, a4.z, a4.w};
#pragma unroll
    for (int e = 0; e < 4; ++e) {
      const int c = k0 + acol + e;
      const float mean = colstats[c] * (1.f / 4096.f);
      float var = colstats[256 + c] * (1.f / 4096.f) - mean * mean;
      var = fmaxf(var, 0.f);
      const float v = (av4[e] - mean) * rsqrtf(var + 1e-5f) * gamma[c] + beta[c];
      av4[e] = fmaxf(v, 0.f);
    }
    const float4 b4 = *(const float4*)(B + (size_t)(k0 + brow) * Ncols + col0 + bcol);
    __syncthreads();
    As[acol + 0][arow] = av4[0]; As[acol + 1][arow] = av4[1];
    As[acol + 2][arow] = av4[2]; As[acol + 3][arow] = av4[3];
    *(float4*)&Bs[brow][bcol] = b4;
    __syncthreads();
#pragma unroll
    for (int k = 0; k < 16; ++k) {
      float av[4], bw[4];
      *(float4*)&av[0] = *(const float4*)&As[k][ty * 4];
      *(float4*)&bw[0] = *(const float4*)&Bs[k][tx * 4];
#pragma unroll
      for (int i = 0; i < 4; ++i)
#pragma unroll
        for (int j = 0; j < 4; ++j) acc[i][j] += av[i] * bw[j];
    }
  }

#pragma unroll
  for (int i = 0; i < 4; ++i) {
    const int r = row0 + ty * 4 + i;
    float4 v;
    v.x = acc[i][0]; v.y = acc[i][1]; v.z = acc[i][2]; v.w = acc[i][3];
    *(float4*)(C + (size_t)r * Ncols + col0 + tx * 4) = v;
  }
}

// ---------------------------------------------------------------------------
// Top-K: one block/row; per-thread cached argmax + shfl_xor butterfly;
// only the winner thread rescans its 16 elements. Tie -> lowest index.
// ---------------------------------------------------------------------------
__global__ __launch_bounds__(256) void topk_kernel(
    const float* __restrict__ adj, float* __restrict__ vals,
    int* __restrict__ idxo, float* __restrict__ dinv) {
  __shared__ float sv[N_NODES];
  __shared__ float rw[4];
  __shared__ int   iw[4];
  const int n = blockIdx.x, tid = threadIdx.x;
  const int lane = tid & 63, wave = tid >> 6;
  const float4* rowp = (const float4*)(adj + (size_t)n * N_NODES);

  float mv = -FLT_MAX; int mi = 0x7FFFFFFF;
  for (int g = tid; g < N_NODES / 4; g += 256) {
    const float4 v4 = rowp[g];
    *(float4*)&sv[g * 4] = v4;
    if (v4.x > mv) { mv = v4.x; mi = g * 4 + 0; }
    if (v4.y > mv) { mv = v4.y; mi = g * 4 + 1; }
    if (v4.z > mv) { mv = v4.z; mi = g * 4 + 2; }
    if (v4.w > mv) { mv = v4.w; mi = g * 4 + 3; }
  }

  float sum = 0.f;
  for (int it = 0; it < TOPK; ++it) {
    float bv = mv; int bi = mi;
#pragma unroll
    for (int off = 1; off < 64; off <<= 1) {
      const float ov = __shfl_xor(bv, off);
      const int   oi = __shfl_xor(bi, off);
      if (ov > bv || (ov == bv && oi < bi)) { bv = ov; bi = oi; }
    }
    if (lane == 0) { rw[wave] = bv; iw[wave] = bi; }
    __syncthreads();
    bv = rw[0]; bi = iw[0];
#pragma unroll
    for (int w = 1; w < 4; ++w) {
      const float ov = rw[w]; const int oi = iw[w];
      if (ov > bv || (ov == bv && oi < bi)) { bv = ov; bi = oi; }
    }
    if (tid == 0) {
      vals[(size_t)n * TOPK + it] = bv;
      idxo[(size_t)n * TOPK + it] = bi;
    }
    sum += bv;
    if (tid == ((bi >> 2) & 255)) {        // owner removes + rescans its 16
      sv[bi] = -FLT_MAX;
      mv = -FLT_MAX; mi = 0x7FFFFFFF;
      for (int g = tid; g < N_NODES / 4; g += 256) {
#pragma unroll
        for (int e = 0; e < 4; ++e) {
          const float v = sv[g * 4 + e];
          if (v > mv) { mv = v; mi = g * 4 + e; }
        }
      }
    }
    __syncthreads();
  }
  if (tid == 0)
    dinv[n] = (sum > 0.f) ? rsqrtf(fmaxf(sum, 1e-12f)) : 0.f;
}

// out[n,f] = bias[f] + sum_k vals[n,k]*dinv[n]*dinv[idx]*Z[idx[n,k], f]
__global__ __launch_bounds__(256) void agg_kernel(
    const float* __restrict__ Z, const float* __restrict__ vals,
    const int* __restrict__ idxo, const float* __restrict__ dinv,
    const float* __restrict__ bias, float* __restrict__ out) {
  const int n = blockIdx.x, f = threadIdx.x;
  const float dn = dinv[n];
  float acc = bias[f];
#pragma unroll
  for (int k = 0; k < TOPK; ++k) {
    const int   j = idxo[n * TOPK + k];
    const float w = vals[n * TOPK + k] * dn * dinv[j];
    acc += w * Z[(size_t)j * 256 + f];
  }
  out[(size_t)n * 256 + f] = acc;
}

// BatchNorm stats: 128 partial slabs of 32 rows, then tree reduce.
__global__ __launch_bounds__(256) void bn_partial(
    const float* __restrict__ x, float* __restrict__ partial) {
  const int b = blockIdx.x, c = threadIdx.x;
  float s = 0.f, s2 = 0.f;
  for (int r = b * 32; r < b * 32 + 32; ++r) {
    const float v = x[(size_t)r * 256 + c];
    s += v; s2 += v * v;
  }
  partial[(size_t)b * 512 + c]       = s;
  partial[(size_t)b * 512 + 256 + c] = s2;
}

__global__ __launch_bounds__(256) void bn_reduce(
    const float* __restrict__ partial, float* __restrict__ colstats) {
  const int j = blockIdx.x, t = threadIdx.x;
  __shared__ float red[128];
  if (t < 128) red[t] = partial[(size_t)t * 512 + j];
  __syncthreads();
  for (int s = 64; s > 0; s >>= 1) {
    if (t < s) red[t] += red[t + s];
    __syncthreads();
  }
  if (t == 0) colstats[j] = red[0];
}

// ---------------------------------------------------------------------------
extern "C" void kernel_launch(void* const* d_in, const int* in_sizes, int n_in,
                              void* d_out, int out_size, void* d_ws, size_t ws_size,
                              hipStream_t stream) {
  const float* probs   = (const float*)d_in[0];
  const float* bbox    = (const float*)d_in[1];
  const float* query   = (const float*)d_in[2];
  const float* node    = (const float*)d_in[3];
  const float* mlp_w1  = (const float*)d_in[4];
  const float* mlp_b1  = (const float*)d_in[5];
  const float* mlp_w2  = (const float*)d_in[6];
  const float* mlp_b2  = (const float*)d_in[7];
  const float* conv_w1 = (const float*)d_in[8];
  const float* conv_b1 = (const float*)d_in[9];
  const float* conv_w2 = (const float*)d_in[10];
  const float* conv_b2 = (const float*)d_in[11];
  const float* gamma   = (const float*)d_in[12];
  const float* beta    = (const float*)d_in[13];

  // --- workspace layout (peak 30,408,704 floats = 121.6 MB; r2 proved 123.2) ---
  float* ws = (float*)d_ws;
  size_t off = 0;
  // R1: a planes [4096][5120] u16 x2 during gemm1; adj + spare afterwards
  float* R1 = ws + off;  off += (size_t)N_NODES * K1PAD;         // 20,971,520 f
  u16* a_hi = (u16*)R1;
  u16* a_lo = a_hi + (size_t)N_NODES * K1PAD;
  float* adj = R1;                                               // 16,777,216 f
  float* spare = R1 + (size_t)N_NODES * N_NODES;                 //  4,194,304 f
  float* Z1   = spare;
  float* vals = spare + (size_t)N_NODES * 256;
  int*   idxo = (int*)(vals + (size_t)N_NODES * TOPK);
  float* dinv = (float*)idxo + (size_t)N_NODES * TOPK;
  float* partial  = dinv + N_NODES;
  float* colstats = partial + 128 * 512;
  // R2: w1t during gemm1; w2t + w1ct afterwards; out1 overlays w1ct
  float* R2 = ws + off;  off += (size_t)HMLP * K1PAD;            //  5,242,880 f
  u16* w1t_hi = (u16*)R2;
  u16* w1t_lo = w1t_hi + (size_t)HMLP * K1PAD;
  u16* w2t_hi = (u16*)R2;
  u16* w2t_lo = w2t_hi + (size_t)N_NODES * HMLP;
  u16* w1ct_hi = (u16*)(R2 + (size_t)N_NODES * HMLP);
  u16* w1ct_lo = w1ct_hi + (size_t)256 * D_DIM;
  float* out1 = R2 + (size_t)N_NODES * HMLP;                     // post-fused2
  // R3: h planes
  float* R3 = ws + off;  off += (size_t)N_NODES * HMLP;          //  4,194,304 f
  u16* h_hi = (u16*)R3;
  u16* h_lo = h_hi + (size_t)N_NODES * HMLP;
  float* Z2 = adj;                       // adj dead after topk

  // 1) prep1: a planes + W1t transpose (merged, 11520 blocks)
  prep1_kernel<<<10240 + 1280, 256, 0, stream>>>(
      query, probs, bbox, mlp_w1, a_hi, a_lo, w1t_hi, w1t_lo);
  // 2) h = relu(Apad @ W1 + b1) -> bf16 hi/lo           (4096 x 1024)
  gemm1_kernel<<<512, 256, 0, stream>>>(
      a_hi, a_lo, w1t_hi, w1t_lo, mlp_b1, h_hi, h_lo);
  // 3) prep2: W2t + W1Ct transposes (merged, 1280 blocks; w1t dead now)
  prep2_kernel<<<1024 + 256, 256, 0, stream>>>(
      mlp_w2, conv_w1, w2t_hi, w2t_lo, w1ct_hi, w1ct_lo);
  // 4) fused: Z1 (128 blocks, band-local) + adj (1024, 2-D XCD tiles)
  fused2_kernel<<<128 + (N_NODES / 128) * (N_NODES / 128), 256, 0, stream>>>(
      h_hi, h_lo, w2t_hi, w2t_lo, mlp_b2, adj, node, w1ct_hi, w1ct_lo, Z1);
  // 5) top-32 per row + dinv
  topk_kernel<<<N_NODES, 256, 0, stream>>>(adj, vals, idxo, dinv);
  // 6) out1 = gather-agg(Z1) + conv_b1   (raw, pre-BN)
  agg_kernel<<<N_NODES, 256, 0, stream>>>(Z1, vals, idxo, dinv, conv_b1, out1);
  // 7) BatchNorm stats
  bn_partial<<<128, 256, 0, stream>>>(out1, partial);
  bn_reduce<<<512, 256, 0, stream>>>(partial, colstats);
  // 8) Z2 = relu(bn(out1)) @ conv_w2  (BN-apply fused into A-load)
  gemm_small_bn<<<dim3(256 / 64, N_NODES / 64), 256, 0, stream>>>(
      out1, colstats, gamma, beta, conv_w2, Z2, N_NODES, 256, 256);
  // 9) out = gather-agg(Z2) + conv_b2
  agg_kernel<<<N_NODES, 256, 0, stream>>>(Z2, vals, idxo, dinv, conv_b2, (float*)d_out);
}